// Round 2
// baseline (3567.979 us; speedup 1.0000x reference)
//
#include <hip/hip_runtime.h>
#include <hip/hip_bf16.h>

#define N_NODES 50000
#define N_EDGES 1600000
#define E_TOT   1650000   // N_EDGES + N_NODES self loops
#define N_PAIRS 2000000
#define N_GRAPHS 50
#define SCAN_NB 196       // ceil(N_NODES/256)

// ---------------- time embedding: h0[:, :128]=x, h0[:,128:384]=swish(feats@tW+tb)
__global__ void k_time_embed(const float* __restrict__ x, const float* __restrict__ t,
                             const float* __restrict__ tW, const float* __restrict__ tb,
                             float* __restrict__ h0) {
    int i = blockIdx.x;
    int tid = threadIdx.x;
    float ta = t[i];                       // T_LIMIT = 1.0
    float s = sinf(ta * 1.5707963267948966f);
    float c = cosf(ta * 1.5707963267948966f);
    if (tid < 128) h0[(size_t)i*384 + tid] = x[(size_t)i*128 + tid];
    float v = s*tW[tid] + c*tW[256+tid] + ta*tW[512+tid] + tb[tid];
    float sw = v / (1.f + __expf(-v));
    h0[(size_t)i*384 + 128 + tid] = sw;
}

// ---------------- CSR build ----------------
__global__ void k_edge_hist(const int* __restrict__ ei, int* __restrict__ deg) {
    int e = blockIdx.x*256 + threadIdx.x;
    if (e >= E_TOT) return;
    int dst = (e < N_EDGES) ? ei[N_EDGES + e] : (e - N_EDGES);
    atomicAdd(&deg[dst], 1);
}

__global__ void k_node_hist(const int* __restrict__ batch, int* __restrict__ gcnt) {
    int i = blockIdx.x*256 + threadIdx.x;
    if (i >= N_NODES) return;
    atomicAdd(&gcnt[batch[i]], 1);
}

__global__ void k_scan1(const int* __restrict__ deg, int* __restrict__ row_ptr,
                        int* __restrict__ bsums) {
    __shared__ int tmp[256];
    int tid = threadIdx.x;
    int i = blockIdx.x*256 + tid;
    int v = (i < N_NODES) ? deg[i] : 0;
    tmp[tid] = v; __syncthreads();
    for (int off = 1; off < 256; off <<= 1) {
        int tv = (tid >= off) ? tmp[tid-off] : 0;
        __syncthreads();
        tmp[tid] += tv;
        __syncthreads();
    }
    int inc = tmp[tid];
    if (i < N_NODES) row_ptr[i] = inc - v;     // block-local exclusive
    if (tid == 255) bsums[blockIdx.x] = inc;
}

__global__ void k_scan2(int* __restrict__ bsums, int nb) {
    __shared__ int tmp[256];
    int tid = threadIdx.x;
    int v = (tid < nb) ? bsums[tid] : 0;
    tmp[tid] = v; __syncthreads();
    for (int off = 1; off < 256; off <<= 1) {
        int tv = (tid >= off) ? tmp[tid-off] : 0;
        __syncthreads();
        tmp[tid] += tv;
        __syncthreads();
    }
    bsums[tid] = tmp[tid] - v;                 // exclusive over block sums
}

__global__ void k_scan3(int* __restrict__ row_ptr, const int* __restrict__ bsums,
                        int* __restrict__ cursor) {
    int i = blockIdx.x*256 + threadIdx.x;
    if (i < N_NODES) {
        int v = row_ptr[i] + bsums[blockIdx.x];
        row_ptr[i] = v;
        cursor[i] = v;
    }
    if (i == 0) row_ptr[N_NODES] = E_TOT;
}

__global__ void k_scatter(const int* __restrict__ ei, int* __restrict__ cursor,
                          int* __restrict__ csr_src) {
    int e = blockIdx.x*256 + threadIdx.x;
    if (e >= E_TOT) return;
    int src, dst;
    if (e < N_EDGES) { src = ei[e]; dst = ei[N_EDGES + e]; }
    else             { src = e - N_EDGES; dst = src; }
    int pos = atomicAdd(&cursor[dst], 1);
    csr_src[pos] = src;
}

// ---------------- dual GEMM: xl = A@Wl + bl, xr = A@Wr + br, A is [N,K], W [K,128]
template<int K>
__global__ __launch_bounds__(128) void k_gemm_dual(
    const float* __restrict__ A, const float* __restrict__ Wl, const float* __restrict__ Wr,
    const float* __restrict__ bl, const float* __restrict__ br,
    float* __restrict__ xl, float* __restrict__ xr) {
    __shared__ float Alds[8*K];
    int tid = threadIdx.x;
    size_t row0 = (size_t)blockIdx.x * 8;
    #pragma unroll
    for (int r = 0; r < 8; ++r)
        for (int kk = tid; kk < K; kk += 128)
            Alds[r*K + kk] = A[(row0 + r)*K + kk];
    __syncthreads();
    float accl[8], accr[8];
    #pragma unroll
    for (int r = 0; r < 8; ++r) { accl[r] = 0.f; accr[r] = 0.f; }
    for (int k = 0; k < K; ++k) {
        float wl = Wl[k*128 + tid];
        float wr = Wr[k*128 + tid];
        #pragma unroll
        for (int r = 0; r < 8; ++r) {
            float a = Alds[r*K + k];
            accl[r] += a * wl;
            accr[r] += a * wr;
        }
    }
    float bll = bl[tid], brr = br[tid];
    #pragma unroll
    for (int r = 0; r < 8; ++r) {
        xl[(row0+r)*128 + tid] = accl[r] + bll;
        xr[(row0+r)*128 + tid] = accr[r] + brr;
    }
}

// ---------------- GATv2 aggregation: one wave per node, online softmax.
// lane l holds channels 2l, 2l+1 (both in head l>>4). Fused graph-LN stats.
// Edge loop unrolled x8 (two independent online-softmax chains A/B merged at
// the end) for 8x memory-level parallelism on the xl gathers.
__global__ __launch_bounds__(256) void k_gat(
    const float* __restrict__ xl, const float* __restrict__ xr,
    const int* __restrict__ row_ptr, const int* __restrict__ csr_src,
    const float* __restrict__ att, const float* __restrict__ bias,
    const int* __restrict__ batch, float* __restrict__ hout,
    float* __restrict__ gsum, float* __restrict__ gsumsq) {
    int wave = (blockIdx.x * 256 + threadIdx.x) >> 6;
    int lane = threadIdx.x & 63;
    if (wave >= N_NODES) return;
    int i = wave;
    int c0 = lane * 2;
    int head = lane >> 4;
    float attv0 = att[head*32 + (c0 & 31)];
    float attv1 = att[head*32 + ((c0+1) & 31)];
    const float2* xl2 = (const float2*)xl;
    const float2* xr2 = (const float2*)xr;
    float2 xrv = xr2[(size_t)i*64 + lane];
    int p0 = row_ptr[i], p1 = row_ptr[i+1];

    float mA = -1e30f, dA = 0.f, aA0 = 0.f, aA1 = 0.f;
    float mB = -1e30f, dB = 0.f, aB0 = 0.f, aB1 = 0.f;

    for (int p = p0; p < p1; p += 8) {
        int   idx[8];
        float2 g[8];
        float pt[8];
        #pragma unroll
        for (int j = 0; j < 8; ++j) {
            int pp = p + j;
            idx[j] = csr_src[(pp < p1) ? pp : (p1 - 1)];
        }
        #pragma unroll
        for (int j = 0; j < 8; ++j)
            g[j] = xl2[(size_t)idx[j]*64 + lane];
        #pragma unroll
        for (int j = 0; j < 8; ++j) {
            float m0 = g[j].x + xrv.x; m0 = (m0 >= 0.f) ? m0 : 0.2f*m0;
            float m1 = g[j].y + xrv.y; m1 = (m1 >= 0.f) ? m1 : 0.2f*m1;
            pt[j] = m0*attv0 + m1*attv1;
        }
        #pragma unroll
        for (int off = 1; off < 16; off <<= 1) {
            #pragma unroll
            for (int j = 0; j < 8; ++j) pt[j] += __shfl_xor(pt[j], off);
        }
        #pragma unroll
        for (int j = 0; j < 8; ++j)
            if (p + j >= p1) pt[j] = -1e30f;     // masked slot -> weight 0

        // chain A: slots 0..3 (always has >=1 valid edge since p < p1)
        {
            float mq = fmaxf(fmaxf(pt[0], pt[1]), fmaxf(pt[2], pt[3]));
            float w0 = __expf(pt[0]-mq), w1 = __expf(pt[1]-mq);
            float w2 = __expf(pt[2]-mq), w3 = __expf(pt[3]-mq);
            float dq  = w0 + w1 + w2 + w3;
            float aq0 = w0*g[0].x + w1*g[1].x + w2*g[2].x + w3*g[3].x;
            float aq1 = w0*g[0].y + w1*g[1].y + w2*g[2].y + w3*g[3].y;
            float mn = fmaxf(mA, mq);
            float sc = __expf(mA - mn), sq = __expf(mq - mn);
            dA  = dA*sc  + dq*sq;
            aA0 = aA0*sc + aq0*sq;
            aA1 = aA1*sc + aq1*sq;
            mA = mn;
        }
        // chain B: slots 4..7 (guard: quad fully masked would corrupt state)
        if (p + 4 < p1) {
            float mq = fmaxf(fmaxf(pt[4], pt[5]), fmaxf(pt[6], pt[7]));
            float w0 = __expf(pt[4]-mq), w1 = __expf(pt[5]-mq);
            float w2 = __expf(pt[6]-mq), w3 = __expf(pt[7]-mq);
            float dq  = w0 + w1 + w2 + w3;
            float aq0 = w0*g[4].x + w1*g[5].x + w2*g[6].x + w3*g[7].x;
            float aq1 = w0*g[4].y + w1*g[5].y + w2*g[6].y + w3*g[7].y;
            float mn = fmaxf(mB, mq);
            float sc = __expf(mB - mn), sq = __expf(mq - mn);
            dB  = dB*sc  + dq*sq;
            aB0 = aB0*sc + aq0*sq;
            aB1 = aB1*sc + aq1*sq;
            mB = mn;
        }
    }
    // merge chains (mB==-1e30 if B never ran -> sB==0)
    float mfin = fmaxf(mA, mB);
    float sA = __expf(mA - mfin), sB = __expf(mB - mfin);
    float denom = dA*sA + dB*sB;
    float acc0  = aA0*sA + aB0*sB;
    float acc1  = aA1*sA + aB1*sB;

    float inv = 1.f / (denom + 1e-16f);
    float v0 = acc0 * inv + bias[c0];
    float v1 = acc1 * inv + bias[c0+1];
    hout[(size_t)i*128 + c0]     = v0;
    hout[(size_t)i*128 + c0 + 1] = v1;
    // fused graph-LN statistics
    float s1 = v0 + v1;
    float s2 = v0*v0 + v1*v1;
    #pragma unroll
    for (int off = 1; off < 64; off <<= 1) {
        s1 += __shfl_xor(s1, off);
        s2 += __shfl_xor(s2, off);
    }
    if (lane == 0) {
        int g = batch[i];
        atomicAdd(&gsum[g], s1);
        atomicAdd(&gsumsq[g], s2);
    }
}

// ---------------- graph layernorm apply ----------------
__global__ void k_ln(const float* __restrict__ hout, const int* __restrict__ batch,
                     const int* __restrict__ gcnt, const float* __restrict__ gsum,
                     const float* __restrict__ gsumsq, const float* __restrict__ w,
                     const float* __restrict__ b, float* __restrict__ hcur) {
    int idx = blockIdx.x*256 + threadIdx.x;
    if (idx >= N_NODES*128) return;
    int i = idx >> 7, c = idx & 127;
    int g = batch[i];
    float cnt = (float)gcnt[g] * 128.f;
    float mean = gsum[g] / cnt;
    float var = gsumsq[g] / cnt - mean*mean;
    var = fmaxf(var, 0.f);
    float rstd = rsqrtf(var + 1e-5f);
    hcur[idx] = (hout[idx] - mean) * rstd * w[c] + b[c];
}

// ---------------- pair scoring: 32 lanes per pair ----------------
__global__ __launch_bounds__(256) void k_pairs(
    const float* __restrict__ h, const int* __restrict__ pi,
    const float* __restrict__ lW, const float* __restrict__ lb,
    float* __restrict__ out) {
    int grp = (blockIdx.x*256 + threadIdx.x) >> 5;
    int q = threadIdx.x & 31;
    if (grp >= N_PAIRS) return;
    int p0 = pi[grp], p1 = pi[N_PAIRS + grp];
    const float4* h4 = (const float4*)h;
    const float4* w4 = (const float4*)lW;
    float4 a = h4[(size_t)p0*32 + q];
    float4 b = h4[(size_t)p1*32 + q];
    float4 w = w4[q];
    float part = a.x*b.x*w.x + a.y*b.y*w.y + a.z*b.z*w.z + a.w*b.w*w.w;
    part += __shfl_xor(part, 1);
    part += __shfl_xor(part, 2);
    part += __shfl_xor(part, 4);
    part += __shfl_xor(part, 8);
    part += __shfl_xor(part, 16);
    if (q == 0) out[grp] = 1.f / (1.f + __expf(-(part + lb[0])));
}

extern "C" void kernel_launch(void* const* d_in, const int* in_sizes, int n_in,
                              void* d_out, int out_size, void* d_ws, size_t ws_size,
                              hipStream_t stream) {
    const float* x     = (const float*)d_in[0];
    const float* t     = (const float*)d_in[1];
    const int*   ei    = (const int*)  d_in[2];
    const int*   pi    = (const int*)  d_in[3];
    const int*   batch = (const int*)  d_in[4];
    const float* tW    = (const float*)d_in[5];
    const float* tb    = (const float*)d_in[6];
    const float* W0l   = (const float*)d_in[7];
    const float* b0l   = (const float*)d_in[8];
    const float* W0r   = (const float*)d_in[9];
    const float* b0r   = (const float*)d_in[10];
    const float* att0  = (const float*)d_in[11];
    const float* bias0 = (const float*)d_in[12];
    const float* Wl    = (const float*)d_in[13];
    const float* bl    = (const float*)d_in[14];
    const float* Wr    = (const float*)d_in[15];
    const float* br    = (const float*)d_in[16];
    const float* att   = (const float*)d_in[17];
    const float* bias  = (const float*)d_in[18];
    const float* lnw   = (const float*)d_in[19];
    const float* lnb   = (const float*)d_in[20];
    const float* lW    = (const float*)d_in[21];
    const float* lb    = (const float*)d_in[22];
    float* out = (float*)d_out;

    char* ws = (char*)d_ws;
    size_t off = 0;
    auto walloc = [&](size_t bytes) -> void* {
        void* p = ws + off;
        off += (bytes + 255) & ~(size_t)255;
        return p;
    };
    float* h0      = (float*)walloc((size_t)N_NODES*384*4);
    float* hcur    = (float*)walloc((size_t)N_NODES*128*4);
    float* hout    = (float*)walloc((size_t)N_NODES*128*4);
    float* xl      = (float*)walloc((size_t)N_NODES*128*4);
    float* xr      = (float*)walloc((size_t)N_NODES*128*4);
    int*   deg     = (int*)  walloc((size_t)N_NODES*4);        // reused as cursor
    int*   row_ptr = (int*)  walloc((size_t)(N_NODES+1)*4);
    int*   csr_src = (int*)  walloc((size_t)E_TOT*4);
    int*   bsums   = (int*)  walloc(256*4);
    int*   gcnt    = (int*)  walloc(64*4);
    float* stats   = (float*)walloc(4*2*64*4);                 // [layer][sum|sumsq][64]

    hipMemsetAsync(deg, 0, (size_t)N_NODES*4, stream);
    hipMemsetAsync(gcnt, 0, 64*4, stream);
    hipMemsetAsync(stats, 0, 4*2*64*4, stream);

    k_time_embed<<<N_NODES, 256, 0, stream>>>(x, t, tW, tb, h0);
    k_edge_hist<<<(E_TOT+255)/256, 256, 0, stream>>>(ei, deg);
    k_node_hist<<<(N_NODES+255)/256, 256, 0, stream>>>(batch, gcnt);
    k_scan1<<<SCAN_NB, 256, 0, stream>>>(deg, row_ptr, bsums);
    k_scan2<<<1, 256, 0, stream>>>(bsums, SCAN_NB);
    k_scan3<<<SCAN_NB, 256, 0, stream>>>(row_ptr, bsums, deg);   // deg becomes cursor
    k_scatter<<<(E_TOT+255)/256, 256, 0, stream>>>(ei, deg, csr_src);

    for (int L = 0; L < 4; ++L) {
        if (L == 0)
            k_gemm_dual<384><<<N_NODES/8, 128, 0, stream>>>(h0, W0l, W0r, b0l, b0r, xl, xr);
        else
            k_gemm_dual<128><<<N_NODES/8, 128, 0, stream>>>(hcur, Wl + (size_t)(L-1)*128*128,
                                                            Wr + (size_t)(L-1)*128*128,
                                                            bl + (L-1)*128, br + (L-1)*128, xl, xr);
        const float* attL  = (L == 0) ? att0  : att  + (size_t)(L-1)*128;
        const float* biasL = (L == 0) ? bias0 : bias + (size_t)(L-1)*128;
        float* gsum   = stats + L*128;
        float* gsumsq = stats + L*128 + 64;
        k_gat<<<N_NODES/4, 256, 0, stream>>>(xl, xr, row_ptr, csr_src, attL, biasL,
                                             batch, hout, gsum, gsumsq);
        k_ln<<<(N_NODES*128+255)/256, 256, 0, stream>>>(hout, batch, gcnt, gsum, gsumsq,
                                                        lnw + L*128, lnb + L*128, hcur);
    }

    k_pairs<<<((size_t)N_PAIRS*32 + 255)/256, 256, 0, stream>>>(hcur, pi, lW, lb, out);
}

// Round 3
// 3563.827 us; speedup vs baseline: 1.0012x; 1.0012x over previous
//
#include <hip/hip_runtime.h>
#include <hip/hip_bf16.h>
#include <hip/hip_fp16.h>

#define N_NODES 50000
#define N_EDGES 1600000
#define E_TOT   1650000   // N_EDGES + N_NODES self loops
#define N_PAIRS 2000000
#define N_GRAPHS 50
#define SCAN_NB 196       // ceil(N_NODES/256)

typedef __attribute__((ext_vector_type(2))) _Float16 half2_t;
typedef __attribute__((ext_vector_type(4))) _Float16 half4_t;

// ---------------- time embedding: h0[:, :128]=x, h0[:,128:384]=swish(feats@tW+tb)
__global__ void k_time_embed(const float* __restrict__ x, const float* __restrict__ t,
                             const float* __restrict__ tW, const float* __restrict__ tb,
                             float* __restrict__ h0) {
    int i = blockIdx.x;
    int tid = threadIdx.x;
    float ta = t[i];                       // T_LIMIT = 1.0
    float s = sinf(ta * 1.5707963267948966f);
    float c = cosf(ta * 1.5707963267948966f);
    if (tid < 128) h0[(size_t)i*384 + tid] = x[(size_t)i*128 + tid];
    float v = s*tW[tid] + c*tW[256+tid] + ta*tW[512+tid] + tb[tid];
    float sw = v / (1.f + __expf(-v));
    h0[(size_t)i*384 + 128 + tid] = sw;
}

// ---------------- CSR build ----------------
__global__ void k_edge_hist(const int* __restrict__ ei, int* __restrict__ deg) {
    int e = blockIdx.x*256 + threadIdx.x;
    if (e >= E_TOT) return;
    int dst = (e < N_EDGES) ? ei[N_EDGES + e] : (e - N_EDGES);
    atomicAdd(&deg[dst], 1);
}

__global__ void k_node_hist(const int* __restrict__ batch, int* __restrict__ gcnt) {
    int i = blockIdx.x*256 + threadIdx.x;
    if (i >= N_NODES) return;
    atomicAdd(&gcnt[batch[i]], 1);
}

__global__ void k_scan1(const int* __restrict__ deg, int* __restrict__ row_ptr,
                        int* __restrict__ bsums) {
    __shared__ int tmp[256];
    int tid = threadIdx.x;
    int i = blockIdx.x*256 + tid;
    int v = (i < N_NODES) ? deg[i] : 0;
    tmp[tid] = v; __syncthreads();
    for (int off = 1; off < 256; off <<= 1) {
        int tv = (tid >= off) ? tmp[tid-off] : 0;
        __syncthreads();
        tmp[tid] += tv;
        __syncthreads();
    }
    int inc = tmp[tid];
    if (i < N_NODES) row_ptr[i] = inc - v;     // block-local exclusive
    if (tid == 255) bsums[blockIdx.x] = inc;
}

__global__ void k_scan2(int* __restrict__ bsums, int nb) {
    __shared__ int tmp[256];
    int tid = threadIdx.x;
    int v = (tid < nb) ? bsums[tid] : 0;
    tmp[tid] = v; __syncthreads();
    for (int off = 1; off < 256; off <<= 1) {
        int tv = (tid >= off) ? tmp[tid-off] : 0;
        __syncthreads();
        tmp[tid] += tv;
        __syncthreads();
    }
    bsums[tid] = tmp[tid] - v;                 // exclusive over block sums
}

__global__ void k_scan3(int* __restrict__ row_ptr, const int* __restrict__ bsums,
                        int* __restrict__ cursor) {
    int i = blockIdx.x*256 + threadIdx.x;
    if (i < N_NODES) {
        int v = row_ptr[i] + bsums[blockIdx.x];
        row_ptr[i] = v;
        cursor[i] = v;
    }
    if (i == 0) row_ptr[N_NODES] = E_TOT;
}

__global__ void k_scatter(const int* __restrict__ ei, int* __restrict__ cursor,
                          int* __restrict__ csr_src) {
    int e = blockIdx.x*256 + threadIdx.x;
    if (e >= E_TOT) return;
    int src, dst;
    if (e < N_EDGES) { src = ei[e]; dst = ei[N_EDGES + e]; }
    else             { src = e - N_EDGES; dst = src; }
    int pos = atomicAdd(&cursor[dst], 1);
    csr_src[pos] = src;
}

// ---------------- dual GEMM: xl = A@Wl + bl (fp16 out), xr = A@Wr + br (fp32)
template<int K>
__global__ __launch_bounds__(128) void k_gemm_dual(
    const float* __restrict__ A, const float* __restrict__ Wl, const float* __restrict__ Wr,
    const float* __restrict__ bl, const float* __restrict__ br,
    _Float16* __restrict__ xl_h, float* __restrict__ xr) {
    __shared__ float Alds[8*K];
    int tid = threadIdx.x;
    size_t row0 = (size_t)blockIdx.x * 8;
    #pragma unroll
    for (int r = 0; r < 8; ++r)
        for (int kk = tid; kk < K; kk += 128)
            Alds[r*K + kk] = A[(row0 + r)*K + kk];
    __syncthreads();
    float accl[8], accr[8];
    #pragma unroll
    for (int r = 0; r < 8; ++r) { accl[r] = 0.f; accr[r] = 0.f; }
    for (int k = 0; k < K; ++k) {
        float wl = Wl[k*128 + tid];
        float wr = Wr[k*128 + tid];
        #pragma unroll
        for (int r = 0; r < 8; ++r) {
            float a = Alds[r*K + k];
            accl[r] += a * wl;
            accr[r] += a * wr;
        }
    }
    float bll = bl[tid], brr = br[tid];
    #pragma unroll
    for (int r = 0; r < 8; ++r) {
        xl_h[(row0+r)*128 + tid] = (_Float16)(accl[r] + bll);
        xr[(row0+r)*128 + tid]   = accr[r] + brr;
    }
}

// ---------------- GATv2 aggregation: one wave per node, online softmax.
// lane l holds channels 2l, 2l+1 (both in head l>>4). Fused graph-LN stats.
// xl gathered in fp16 (256B/row) — the random-gather path is byte-throughput
// bound, fp16 halves bytes and lines per row. All math fp32.
__global__ __launch_bounds__(256) void k_gat(
    const _Float16* __restrict__ xl_h, const float* __restrict__ xr,
    const int* __restrict__ row_ptr, const int* __restrict__ csr_src,
    const float* __restrict__ att, const float* __restrict__ bias,
    const int* __restrict__ batch, float* __restrict__ hout,
    float* __restrict__ gsum, float* __restrict__ gsumsq) {
    int wave = (blockIdx.x * 256 + threadIdx.x) >> 6;
    int lane = threadIdx.x & 63;
    if (wave >= N_NODES) return;
    int i = wave;
    int c0 = lane * 2;
    int head = lane >> 4;
    float attv0 = att[head*32 + (c0 & 31)];
    float attv1 = att[head*32 + ((c0+1) & 31)];
    const half2_t* xlh = (const half2_t*)xl_h;
    const float2* xr2 = (const float2*)xr;
    float2 xrv = xr2[(size_t)i*64 + lane];
    int p0 = row_ptr[i], p1 = row_ptr[i+1];

    float mA = -1e30f, dA = 0.f, aA0 = 0.f, aA1 = 0.f;
    float mB = -1e30f, dB = 0.f, aB0 = 0.f, aB1 = 0.f;

    for (int p = p0; p < p1; p += 8) {
        int   idx[8];
        half2_t g[8];
        float gx[8], gy[8];
        float pt[8];
        #pragma unroll
        for (int j = 0; j < 8; ++j) {
            int pp = p + j;
            idx[j] = csr_src[(pp < p1) ? pp : (p1 - 1)];
        }
        #pragma unroll
        for (int j = 0; j < 8; ++j)
            g[j] = xlh[(size_t)idx[j]*64 + lane];
        #pragma unroll
        for (int j = 0; j < 8; ++j) { gx[j] = (float)g[j].x; gy[j] = (float)g[j].y; }
        #pragma unroll
        for (int j = 0; j < 8; ++j) {
            float m0 = gx[j] + xrv.x; m0 = (m0 >= 0.f) ? m0 : 0.2f*m0;
            float m1 = gy[j] + xrv.y; m1 = (m1 >= 0.f) ? m1 : 0.2f*m1;
            pt[j] = m0*attv0 + m1*attv1;
        }
        #pragma unroll
        for (int off = 1; off < 16; off <<= 1) {
            #pragma unroll
            for (int j = 0; j < 8; ++j) pt[j] += __shfl_xor(pt[j], off);
        }
        #pragma unroll
        for (int j = 0; j < 8; ++j)
            if (p + j >= p1) pt[j] = -1e30f;     // masked slot -> weight 0

        // chain A: slots 0..3 (always has >=1 valid edge since p < p1)
        {
            float mq = fmaxf(fmaxf(pt[0], pt[1]), fmaxf(pt[2], pt[3]));
            float w0 = __expf(pt[0]-mq), w1 = __expf(pt[1]-mq);
            float w2 = __expf(pt[2]-mq), w3 = __expf(pt[3]-mq);
            float dq  = w0 + w1 + w2 + w3;
            float aq0 = w0*gx[0] + w1*gx[1] + w2*gx[2] + w3*gx[3];
            float aq1 = w0*gy[0] + w1*gy[1] + w2*gy[2] + w3*gy[3];
            float mn = fmaxf(mA, mq);
            float sc = __expf(mA - mn), sq = __expf(mq - mn);
            dA  = dA*sc  + dq*sq;
            aA0 = aA0*sc + aq0*sq;
            aA1 = aA1*sc + aq1*sq;
            mA = mn;
        }
        // chain B: slots 4..7 (guard: quad fully masked would corrupt state)
        if (p + 4 < p1) {
            float mq = fmaxf(fmaxf(pt[4], pt[5]), fmaxf(pt[6], pt[7]));
            float w0 = __expf(pt[4]-mq), w1 = __expf(pt[5]-mq);
            float w2 = __expf(pt[6]-mq), w3 = __expf(pt[7]-mq);
            float dq  = w0 + w1 + w2 + w3;
            float aq0 = w0*gx[4] + w1*gx[5] + w2*gx[6] + w3*gx[7];
            float aq1 = w0*gy[4] + w1*gy[5] + w2*gy[6] + w3*gy[7];
            float mn = fmaxf(mB, mq);
            float sc = __expf(mB - mn), sq = __expf(mq - mn);
            dB  = dB*sc  + dq*sq;
            aB0 = aB0*sc + aq0*sq;
            aB1 = aB1*sc + aq1*sq;
            mB = mn;
        }
    }
    // merge chains (mB==-1e30 if B never ran -> sB==0)
    float mfin = fmaxf(mA, mB);
    float sA = __expf(mA - mfin), sB = __expf(mB - mfin);
    float denom = dA*sA + dB*sB;
    float acc0  = aA0*sA + aB0*sB;
    float acc1  = aA1*sA + aB1*sB;

    float inv = 1.f / (denom + 1e-16f);
    float v0 = acc0 * inv + bias[c0];
    float v1 = acc1 * inv + bias[c0+1];
    hout[(size_t)i*128 + c0]     = v0;
    hout[(size_t)i*128 + c0 + 1] = v1;
    // fused graph-LN statistics
    float s1 = v0 + v1;
    float s2 = v0*v0 + v1*v1;
    #pragma unroll
    for (int off = 1; off < 64; off <<= 1) {
        s1 += __shfl_xor(s1, off);
        s2 += __shfl_xor(s2, off);
    }
    if (lane == 0) {
        int g = batch[i];
        atomicAdd(&gsum[g], s1);
        atomicAdd(&gsumsq[g], s2);
    }
}

// ---------------- graph layernorm apply (writes fp32 for GEMM + fp16 for gathers)
__global__ void k_ln(const float* __restrict__ hout, const int* __restrict__ batch,
                     const int* __restrict__ gcnt, const float* __restrict__ gsum,
                     const float* __restrict__ gsumsq, const float* __restrict__ w,
                     const float* __restrict__ b, float* __restrict__ hcur,
                     _Float16* __restrict__ hb) {
    int idx = blockIdx.x*256 + threadIdx.x;
    if (idx >= N_NODES*128) return;
    int i = idx >> 7, c = idx & 127;
    int g = batch[i];
    float cnt = (float)gcnt[g] * 128.f;
    float mean = gsum[g] / cnt;
    float var = gsumsq[g] / cnt - mean*mean;
    var = fmaxf(var, 0.f);
    float rstd = rsqrtf(var + 1e-5f);
    float v = (hout[idx] - mean) * rstd * w[c] + b[c];
    hcur[idx] = v;
    hb[idx] = (_Float16)v;
}

// ---------------- pair scoring: 32 lanes per pair, fp16 gathers ----------------
__global__ __launch_bounds__(256) void k_pairs(
    const _Float16* __restrict__ hb, const int* __restrict__ pi,
    const float* __restrict__ lW, const float* __restrict__ lb,
    float* __restrict__ out) {
    int grp = (blockIdx.x*256 + threadIdx.x) >> 5;
    int q = threadIdx.x & 31;
    if (grp >= N_PAIRS) return;
    int p0 = pi[grp], p1 = pi[N_PAIRS + grp];
    const half4_t* h4 = (const half4_t*)hb;
    const float4* w4 = (const float4*)lW;
    half4_t a = h4[(size_t)p0*32 + q];
    half4_t b = h4[(size_t)p1*32 + q];
    float4 w = w4[q];
    float part = (float)a.x*(float)b.x*w.x + (float)a.y*(float)b.y*w.y
               + (float)a.z*(float)b.z*w.z + (float)a.w*(float)b.w*w.w;
    part += __shfl_xor(part, 1);
    part += __shfl_xor(part, 2);
    part += __shfl_xor(part, 4);
    part += __shfl_xor(part, 8);
    part += __shfl_xor(part, 16);
    if (q == 0) out[grp] = 1.f / (1.f + __expf(-(part + lb[0])));
}

extern "C" void kernel_launch(void* const* d_in, const int* in_sizes, int n_in,
                              void* d_out, int out_size, void* d_ws, size_t ws_size,
                              hipStream_t stream) {
    const float* x     = (const float*)d_in[0];
    const float* t     = (const float*)d_in[1];
    const int*   ei    = (const int*)  d_in[2];
    const int*   pi    = (const int*)  d_in[3];
    const int*   batch = (const int*)  d_in[4];
    const float* tW    = (const float*)d_in[5];
    const float* tb    = (const float*)d_in[6];
    const float* W0l   = (const float*)d_in[7];
    const float* b0l   = (const float*)d_in[8];
    const float* W0r   = (const float*)d_in[9];
    const float* b0r   = (const float*)d_in[10];
    const float* att0  = (const float*)d_in[11];
    const float* bias0 = (const float*)d_in[12];
    const float* Wl    = (const float*)d_in[13];
    const float* bl    = (const float*)d_in[14];
    const float* Wr    = (const float*)d_in[15];
    const float* br    = (const float*)d_in[16];
    const float* att   = (const float*)d_in[17];
    const float* bias  = (const float*)d_in[18];
    const float* lnw   = (const float*)d_in[19];
    const float* lnb   = (const float*)d_in[20];
    const float* lW    = (const float*)d_in[21];
    const float* lb    = (const float*)d_in[22];
    float* out = (float*)d_out;

    char* ws = (char*)d_ws;
    size_t off = 0;
    auto walloc = [&](size_t bytes) -> void* {
        void* p = ws + off;
        off += (bytes + 255) & ~(size_t)255;
        return p;
    };
    float*     h0      = (float*)    walloc((size_t)N_NODES*384*4);
    float*     hcur    = (float*)    walloc((size_t)N_NODES*128*4);
    float*     hout    = (float*)    walloc((size_t)N_NODES*128*4);
    _Float16*  xl_h    = (_Float16*) walloc((size_t)N_NODES*128*2);
    float*     xr      = (float*)    walloc((size_t)N_NODES*128*4);
    _Float16*  hb      = (_Float16*) walloc((size_t)N_NODES*128*2);
    int*       deg     = (int*)      walloc((size_t)N_NODES*4);   // reused as cursor
    int*       row_ptr = (int*)      walloc((size_t)(N_NODES+1)*4);
    int*       csr_src = (int*)      walloc((size_t)E_TOT*4);
    int*       bsums   = (int*)      walloc(256*4);
    int*       gcnt    = (int*)      walloc(64*4);
    float*     stats   = (float*)    walloc(4*2*64*4);            // [layer][sum|sumsq][64]

    hipMemsetAsync(deg, 0, (size_t)N_NODES*4, stream);
    hipMemsetAsync(gcnt, 0, 64*4, stream);
    hipMemsetAsync(stats, 0, 4*2*64*4, stream);

    k_time_embed<<<N_NODES, 256, 0, stream>>>(x, t, tW, tb, h0);
    k_edge_hist<<<(E_TOT+255)/256, 256, 0, stream>>>(ei, deg);
    k_node_hist<<<(N_NODES+255)/256, 256, 0, stream>>>(batch, gcnt);
    k_scan1<<<SCAN_NB, 256, 0, stream>>>(deg, row_ptr, bsums);
    k_scan2<<<1, 256, 0, stream>>>(bsums, SCAN_NB);
    k_scan3<<<SCAN_NB, 256, 0, stream>>>(row_ptr, bsums, deg);   // deg becomes cursor
    k_scatter<<<(E_TOT+255)/256, 256, 0, stream>>>(ei, deg, csr_src);

    for (int L = 0; L < 4; ++L) {
        if (L == 0)
            k_gemm_dual<384><<<N_NODES/8, 128, 0, stream>>>(h0, W0l, W0r, b0l, b0r, xl_h, xr);
        else
            k_gemm_dual<128><<<N_NODES/8, 128, 0, stream>>>(hcur, Wl + (size_t)(L-1)*128*128,
                                                            Wr + (size_t)(L-1)*128*128,
                                                            bl + (L-1)*128, br + (L-1)*128, xl_h, xr);
        const float* attL  = (L == 0) ? att0  : att  + (size_t)(L-1)*128;
        const float* biasL = (L == 0) ? bias0 : bias + (size_t)(L-1)*128;
        float* gsum   = stats + L*128;
        float* gsumsq = stats + L*128 + 64;
        k_gat<<<N_NODES/4, 256, 0, stream>>>(xl_h, xr, row_ptr, csr_src, attL, biasL,
                                             batch, hout, gsum, gsumsq);
        k_ln<<<(N_NODES*128+255)/256, 256, 0, stream>>>(hout, batch, gcnt, gsum, gsumsq,
                                                        lnw + L*128, lnb + L*128, hcur, hb);
    }

    k_pairs<<<((size_t)N_PAIRS*32 + 255)/256, 256, 0, stream>>>(hb, pi, lW, lb, out);
}

// Round 4
// 1679.264 us; speedup vs baseline: 2.1247x; 2.1223x over previous
//
#include <hip/hip_runtime.h>
#include <hip/hip_bf16.h>
#include <hip/hip_fp16.h>

#define N_NODES 50000
#define N_EDGES 1600000
#define E_TOT   1650000   // N_EDGES + N_NODES self loops
#define N_PAIRS 2000000
#define N_GRAPHS 50
#define SCAN_NB 196       // ceil(N_NODES/256)

typedef __attribute__((ext_vector_type(2))) _Float16 half2_t;
typedef __attribute__((ext_vector_type(4))) _Float16 half4_t;

// ---------------- time embedding: h0[:, :128]=x, h0[:,128:384]=swish(feats@tW+tb)
__global__ void k_time_embed(const float* __restrict__ x, const float* __restrict__ t,
                             const float* __restrict__ tW, const float* __restrict__ tb,
                             float* __restrict__ h0) {
    int i = blockIdx.x;
    int tid = threadIdx.x;
    float ta = t[i];                       // T_LIMIT = 1.0
    float s = sinf(ta * 1.5707963267948966f);
    float c = cosf(ta * 1.5707963267948966f);
    if (tid < 128) h0[(size_t)i*384 + tid] = x[(size_t)i*128 + tid];
    float v = s*tW[tid] + c*tW[256+tid] + ta*tW[512+tid] + tb[tid];
    float sw = v / (1.f + __expf(-v));
    h0[(size_t)i*384 + 128 + tid] = sw;
}

// ---------------- CSR build ----------------
__global__ void k_edge_hist(const int* __restrict__ ei, int* __restrict__ deg) {
    int e = blockIdx.x*256 + threadIdx.x;
    if (e >= E_TOT) return;
    int dst = (e < N_EDGES) ? ei[N_EDGES + e] : (e - N_EDGES);
    atomicAdd(&deg[dst], 1);
}

// batch is sorted: derive graph offsets without atomics
__global__ void k_goff(const int* __restrict__ batch, int* __restrict__ goff) {
    int i = blockIdx.x*256 + threadIdx.x;
    if (i >= N_NODES) return;
    int bi = batch[i];
    if (i == 0) {
        for (int g = 0; g <= bi; ++g) goff[g] = 0;
    } else {
        int bp = batch[i-1];
        for (int g = bp+1; g <= bi; ++g) goff[g] = i;
    }
    if (i == N_NODES-1) {
        for (int g = bi+1; g <= N_GRAPHS; ++g) goff[g] = N_NODES;
    }
}

__global__ void k_scan1(const int* __restrict__ deg, int* __restrict__ row_ptr,
                        int* __restrict__ bsums) {
    __shared__ int tmp[256];
    int tid = threadIdx.x;
    int i = blockIdx.x*256 + tid;
    int v = (i < N_NODES) ? deg[i] : 0;
    tmp[tid] = v; __syncthreads();
    for (int off = 1; off < 256; off <<= 1) {
        int tv = (tid >= off) ? tmp[tid-off] : 0;
        __syncthreads();
        tmp[tid] += tv;
        __syncthreads();
    }
    int inc = tmp[tid];
    if (i < N_NODES) row_ptr[i] = inc - v;     // block-local exclusive
    if (tid == 255) bsums[blockIdx.x] = inc;
}

__global__ void k_scan2(int* __restrict__ bsums, int nb) {
    __shared__ int tmp[256];
    int tid = threadIdx.x;
    int v = (tid < nb) ? bsums[tid] : 0;
    tmp[tid] = v; __syncthreads();
    for (int off = 1; off < 256; off <<= 1) {
        int tv = (tid >= off) ? tmp[tid-off] : 0;
        __syncthreads();
        tmp[tid] += tv;
        __syncthreads();
    }
    bsums[tid] = tmp[tid] - v;                 // exclusive over block sums
}

__global__ void k_scan3(int* __restrict__ row_ptr, const int* __restrict__ bsums,
                        int* __restrict__ cursor) {
    int i = blockIdx.x*256 + threadIdx.x;
    if (i < N_NODES) {
        int v = row_ptr[i] + bsums[blockIdx.x];
        row_ptr[i] = v;
        cursor[i] = v;
    }
    if (i == 0) row_ptr[N_NODES] = E_TOT;
}

__global__ void k_scatter(const int* __restrict__ ei, int* __restrict__ cursor,
                          int* __restrict__ csr_src) {
    int e = blockIdx.x*256 + threadIdx.x;
    if (e >= E_TOT) return;
    int src, dst;
    if (e < N_EDGES) { src = ei[e]; dst = ei[N_EDGES + e]; }
    else             { src = e - N_EDGES; dst = src; }
    int pos = atomicAdd(&cursor[dst], 1);
    csr_src[pos] = src;
}

// ---------------- dual GEMM: xl = A@Wl + bl (fp16 out), xr = A@Wr + br (fp32)
template<int K>
__global__ __launch_bounds__(128) void k_gemm_dual(
    const float* __restrict__ A, const float* __restrict__ Wl, const float* __restrict__ Wr,
    const float* __restrict__ bl, const float* __restrict__ br,
    _Float16* __restrict__ xl_h, float* __restrict__ xr) {
    __shared__ float Alds[8*K];
    int tid = threadIdx.x;
    size_t row0 = (size_t)blockIdx.x * 8;
    #pragma unroll
    for (int r = 0; r < 8; ++r)
        for (int kk = tid; kk < K; kk += 128)
            Alds[r*K + kk] = A[(row0 + r)*K + kk];
    __syncthreads();
    float accl[8], accr[8];
    #pragma unroll
    for (int r = 0; r < 8; ++r) { accl[r] = 0.f; accr[r] = 0.f; }
    for (int k = 0; k < K; ++k) {
        float wl = Wl[k*128 + tid];
        float wr = Wr[k*128 + tid];
        #pragma unroll
        for (int r = 0; r < 8; ++r) {
            float a = Alds[r*K + k];
            accl[r] += a * wl;
            accr[r] += a * wr;
        }
    }
    float bll = bl[tid], brr = br[tid];
    #pragma unroll
    for (int r = 0; r < 8; ++r) {
        xl_h[(row0+r)*128 + tid] = (_Float16)(accl[r] + bll);
        xr[(row0+r)*128 + tid]   = accr[r] + brr;
    }
}

// ---------------- GATv2 aggregation: one wave per node, online softmax.
// lane l holds channels 2l, 2l+1 (both in head l>>4). LN stats written per-node
// (plain store) — NO global atomics (sorted batch made same-slot atomics the
// serializing bottleneck in R1-R3).
__global__ __launch_bounds__(256) void k_gat(
    const _Float16* __restrict__ xl_h, const float* __restrict__ xr,
    const int* __restrict__ row_ptr, const int* __restrict__ csr_src,
    const float* __restrict__ att, const float* __restrict__ bias,
    float* __restrict__ hout, float2* __restrict__ nstats) {
    int wave = (blockIdx.x * 256 + threadIdx.x) >> 6;
    int lane = threadIdx.x & 63;
    if (wave >= N_NODES) return;
    int i = wave;
    int c0 = lane * 2;
    int head = lane >> 4;
    float attv0 = att[head*32 + (c0 & 31)];
    float attv1 = att[head*32 + ((c0+1) & 31)];
    const half2_t* xlh = (const half2_t*)xl_h;
    const float2* xr2 = (const float2*)xr;
    float2 xrv = xr2[(size_t)i*64 + lane];
    int p0 = row_ptr[i], p1 = row_ptr[i+1];

    float mA = -1e30f, dA = 0.f, aA0 = 0.f, aA1 = 0.f;
    float mB = -1e30f, dB = 0.f, aB0 = 0.f, aB1 = 0.f;

    for (int p = p0; p < p1; p += 8) {
        int   idx[8];
        half2_t g[8];
        float gx[8], gy[8];
        float pt[8];
        #pragma unroll
        for (int j = 0; j < 8; ++j) {
            int pp = p + j;
            idx[j] = csr_src[(pp < p1) ? pp : (p1 - 1)];
        }
        #pragma unroll
        for (int j = 0; j < 8; ++j)
            g[j] = xlh[(size_t)idx[j]*64 + lane];
        #pragma unroll
        for (int j = 0; j < 8; ++j) { gx[j] = (float)g[j].x; gy[j] = (float)g[j].y; }
        #pragma unroll
        for (int j = 0; j < 8; ++j) {
            float m0 = gx[j] + xrv.x; m0 = (m0 >= 0.f) ? m0 : 0.2f*m0;
            float m1 = gy[j] + xrv.y; m1 = (m1 >= 0.f) ? m1 : 0.2f*m1;
            pt[j] = m0*attv0 + m1*attv1;
        }
        #pragma unroll
        for (int off = 1; off < 16; off <<= 1) {
            #pragma unroll
            for (int j = 0; j < 8; ++j) pt[j] += __shfl_xor(pt[j], off);
        }
        #pragma unroll
        for (int j = 0; j < 8; ++j)
            if (p + j >= p1) pt[j] = -1e30f;     // masked slot -> weight 0

        // chain A: slots 0..3 (always has >=1 valid edge since p < p1)
        {
            float mq = fmaxf(fmaxf(pt[0], pt[1]), fmaxf(pt[2], pt[3]));
            float w0 = __expf(pt[0]-mq), w1 = __expf(pt[1]-mq);
            float w2 = __expf(pt[2]-mq), w3 = __expf(pt[3]-mq);
            float dq  = w0 + w1 + w2 + w3;
            float aq0 = w0*gx[0] + w1*gx[1] + w2*gx[2] + w3*gx[3];
            float aq1 = w0*gy[0] + w1*gy[1] + w2*gy[2] + w3*gy[3];
            float mn = fmaxf(mA, mq);
            float sc = __expf(mA - mn), sq = __expf(mq - mn);
            dA  = dA*sc  + dq*sq;
            aA0 = aA0*sc + aq0*sq;
            aA1 = aA1*sc + aq1*sq;
            mA = mn;
        }
        // chain B: slots 4..7 (guard: quad fully masked would corrupt state)
        if (p + 4 < p1) {
            float mq = fmaxf(fmaxf(pt[4], pt[5]), fmaxf(pt[6], pt[7]));
            float w0 = __expf(pt[4]-mq), w1 = __expf(pt[5]-mq);
            float w2 = __expf(pt[6]-mq), w3 = __expf(pt[7]-mq);
            float dq  = w0 + w1 + w2 + w3;
            float aq0 = w0*gx[4] + w1*gx[5] + w2*gx[6] + w3*gx[7];
            float aq1 = w0*gy[4] + w1*gy[5] + w2*gy[6] + w3*gy[7];
            float mn = fmaxf(mB, mq);
            float sc = __expf(mB - mn), sq = __expf(mq - mn);
            dB  = dB*sc  + dq*sq;
            aB0 = aB0*sc + aq0*sq;
            aB1 = aB1*sc + aq1*sq;
            mB = mn;
        }
    }
    // merge chains (mB==-1e30 if B never ran -> sB==0)
    float mfin = fmaxf(mA, mB);
    float sA = __expf(mA - mfin), sB = __expf(mB - mfin);
    float denom = dA*sA + dB*sB;
    float acc0  = aA0*sA + aB0*sB;
    float acc1  = aA1*sA + aB1*sB;

    float inv = 1.f / (denom + 1e-16f);
    float v0 = acc0 * inv + bias[c0];
    float v1 = acc1 * inv + bias[c0+1];
    hout[(size_t)i*128 + c0]     = v0;
    hout[(size_t)i*128 + c0 + 1] = v1;
    // per-node LN statistics (reduced per-graph by k_graph_red, no atomics)
    float s1 = v0 + v1;
    float s2 = v0*v0 + v1*v1;
    #pragma unroll
    for (int off = 1; off < 64; off <<= 1) {
        s1 += __shfl_xor(s1, off);
        s2 += __shfl_xor(s2, off);
    }
    if (lane == 0) nstats[i] = make_float2(s1, s2);
}

// ---------------- per-graph reduction of node stats (plain stores) ----------
__global__ __launch_bounds__(256) void k_graph_red(
    const float2* __restrict__ nstats, const int* __restrict__ goff,
    float* __restrict__ gsum, float* __restrict__ gsumsq) {
    __shared__ float l1[256], l2[256];
    int g = blockIdx.x;
    int tid = threadIdx.x;
    int a = goff[g], b = goff[g+1];
    float s1 = 0.f, s2 = 0.f;
    for (int i = a + tid; i < b; i += 256) {
        float2 v = nstats[i];
        s1 += v.x; s2 += v.y;
    }
    l1[tid] = s1; l2[tid] = s2; __syncthreads();
    for (int off = 128; off > 0; off >>= 1) {
        if (tid < off) { l1[tid] += l1[tid+off]; l2[tid] += l2[tid+off]; }
        __syncthreads();
    }
    if (tid == 0) { gsum[g] = l1[0]; gsumsq[g] = l2[0]; }
}

// ---------------- graph layernorm apply (writes fp32 for GEMM + fp16 for gathers)
__global__ void k_ln(const float* __restrict__ hout, const int* __restrict__ batch,
                     const int* __restrict__ goff, const float* __restrict__ gsum,
                     const float* __restrict__ gsumsq, const float* __restrict__ w,
                     const float* __restrict__ b, float* __restrict__ hcur,
                     _Float16* __restrict__ hb) {
    int idx = blockIdx.x*256 + threadIdx.x;
    if (idx >= N_NODES*128) return;
    int i = idx >> 7, c = idx & 127;
    int g = batch[i];
    float cnt = (float)(goff[g+1] - goff[g]) * 128.f;
    cnt = fmaxf(cnt, 1.f);
    float mean = gsum[g] / cnt;
    float var = gsumsq[g] / cnt - mean*mean;
    var = fmaxf(var, 0.f);
    float rstd = rsqrtf(var + 1e-5f);
    float v = (hout[idx] - mean) * rstd * w[c] + b[c];
    hcur[idx] = v;
    hb[idx] = (_Float16)v;
}

// ---------------- pair scoring: 32 lanes per pair, fp16 gathers ----------------
__global__ __launch_bounds__(256) void k_pairs(
    const _Float16* __restrict__ hb, const int* __restrict__ pi,
    const float* __restrict__ lW, const float* __restrict__ lb,
    float* __restrict__ out) {
    int grp = (blockIdx.x*256 + threadIdx.x) >> 5;
    int q = threadIdx.x & 31;
    if (grp >= N_PAIRS) return;
    int p0 = pi[grp], p1 = pi[N_PAIRS + grp];
    const half4_t* h4 = (const half4_t*)hb;
    const float4* w4 = (const float4*)lW;
    half4_t a = h4[(size_t)p0*32 + q];
    half4_t b = h4[(size_t)p1*32 + q];
    float4 w = w4[q];
    float part = (float)a.x*(float)b.x*w.x + (float)a.y*(float)b.y*w.y
               + (float)a.z*(float)b.z*w.z + (float)a.w*(float)b.w*w.w;
    part += __shfl_xor(part, 1);
    part += __shfl_xor(part, 2);
    part += __shfl_xor(part, 4);
    part += __shfl_xor(part, 8);
    part += __shfl_xor(part, 16);
    if (q == 0) out[grp] = 1.f / (1.f + __expf(-(part + lb[0])));
}

extern "C" void kernel_launch(void* const* d_in, const int* in_sizes, int n_in,
                              void* d_out, int out_size, void* d_ws, size_t ws_size,
                              hipStream_t stream) {
    const float* x     = (const float*)d_in[0];
    const float* t     = (const float*)d_in[1];
    const int*   ei    = (const int*)  d_in[2];
    const int*   pi    = (const int*)  d_in[3];
    const int*   batch = (const int*)  d_in[4];
    const float* tW    = (const float*)d_in[5];
    const float* tb    = (const float*)d_in[6];
    const float* W0l   = (const float*)d_in[7];
    const float* b0l   = (const float*)d_in[8];
    const float* W0r   = (const float*)d_in[9];
    const float* b0r   = (const float*)d_in[10];
    const float* att0  = (const float*)d_in[11];
    const float* bias0 = (const float*)d_in[12];
    const float* Wl    = (const float*)d_in[13];
    const float* bl    = (const float*)d_in[14];
    const float* Wr    = (const float*)d_in[15];
    const float* br    = (const float*)d_in[16];
    const float* att   = (const float*)d_in[17];
    const float* bias  = (const float*)d_in[18];
    const float* lnw   = (const float*)d_in[19];
    const float* lnb   = (const float*)d_in[20];
    const float* lW    = (const float*)d_in[21];
    const float* lb    = (const float*)d_in[22];
    float* out = (float*)d_out;

    char* ws = (char*)d_ws;
    size_t off = 0;
    auto walloc = [&](size_t bytes) -> void* {
        void* p = ws + off;
        off += (bytes + 255) & ~(size_t)255;
        return p;
    };
    float*     h0      = (float*)    walloc((size_t)N_NODES*384*4);
    float*     hcur    = (float*)    walloc((size_t)N_NODES*128*4);
    float*     hout    = (float*)    walloc((size_t)N_NODES*128*4);
    _Float16*  xl_h    = (_Float16*) walloc((size_t)N_NODES*128*2);
    float*     xr      = (float*)    walloc((size_t)N_NODES*128*4);
    _Float16*  hb      = (_Float16*) walloc((size_t)N_NODES*128*2);
    int*       deg     = (int*)      walloc((size_t)N_NODES*4);   // reused as cursor
    int*       row_ptr = (int*)      walloc((size_t)(N_NODES+1)*4);
    int*       csr_src = (int*)      walloc((size_t)E_TOT*4);
    int*       bsums   = (int*)      walloc(256*4);
    int*       goff    = (int*)      walloc(64*4);
    float2*    nstats  = (float2*)   walloc((size_t)N_NODES*8);
    float*     stats   = (float*)    walloc(2*64*4);              // [sum|sumsq][64]

    hipMemsetAsync(deg, 0, (size_t)N_NODES*4, stream);

    k_time_embed<<<N_NODES, 256, 0, stream>>>(x, t, tW, tb, h0);
    k_edge_hist<<<(E_TOT+255)/256, 256, 0, stream>>>(ei, deg);
    k_goff<<<SCAN_NB, 256, 0, stream>>>(batch, goff);
    k_scan1<<<SCAN_NB, 256, 0, stream>>>(deg, row_ptr, bsums);
    k_scan2<<<1, 256, 0, stream>>>(bsums, SCAN_NB);
    k_scan3<<<SCAN_NB, 256, 0, stream>>>(row_ptr, bsums, deg);   // deg becomes cursor
    k_scatter<<<(E_TOT+255)/256, 256, 0, stream>>>(ei, deg, csr_src);

    float* gsum   = stats;
    float* gsumsq = stats + 64;
    for (int L = 0; L < 4; ++L) {
        if (L == 0)
            k_gemm_dual<384><<<N_NODES/8, 128, 0, stream>>>(h0, W0l, W0r, b0l, b0r, xl_h, xr);
        else
            k_gemm_dual<128><<<N_NODES/8, 128, 0, stream>>>(hcur, Wl + (size_t)(L-1)*128*128,
                                                            Wr + (size_t)(L-1)*128*128,
                                                            bl + (L-1)*128, br + (L-1)*128, xl_h, xr);
        const float* attL  = (L == 0) ? att0  : att  + (size_t)(L-1)*128;
        const float* biasL = (L == 0) ? bias0 : bias + (size_t)(L-1)*128;
        k_gat<<<N_NODES/4, 256, 0, stream>>>(xl_h, xr, row_ptr, csr_src, attL, biasL,
                                             hout, nstats);
        k_graph_red<<<N_GRAPHS, 256, 0, stream>>>(nstats, goff, gsum, gsumsq);
        k_ln<<<(N_NODES*128+255)/256, 256, 0, stream>>>(hout, batch, goff, gsum, gsumsq,
                                                        lnw + L*128, lnb + L*128, hcur, hb);
    }

    k_pairs<<<((size_t)N_PAIRS*32 + 255)/256, 256, 0, stream>>>(hb, pi, lW, lb, out);
}

// Round 5
// 1364.877 us; speedup vs baseline: 2.6141x; 1.2303x over previous
//
#include <hip/hip_runtime.h>
#include <hip/hip_bf16.h>
#include <hip/hip_fp16.h>

#define N_NODES 50000
#define N_EDGES 1600000
#define E_TOT   1650000   // N_EDGES + N_NODES self loops
#define N_PAIRS 2000000
#define N_GRAPHS 50
#define SCAN_NB 196       // ceil(N_NODES/256)

typedef __attribute__((ext_vector_type(2))) _Float16 half2_t;
typedef __attribute__((ext_vector_type(4))) _Float16 half4_t;
typedef __attribute__((ext_vector_type(8))) _Float16 half8_t;
typedef __attribute__((ext_vector_type(4))) float floatx4;

// ---------------- time embedding: h0h[:, :128]=x, h0h[:,128:384]=swish(...) (fp16 out)
__global__ void k_time_embed(const float* __restrict__ x, const float* __restrict__ t,
                             const float* __restrict__ tW, const float* __restrict__ tb,
                             _Float16* __restrict__ h0h) {
    int i = blockIdx.x;
    int tid = threadIdx.x;
    float ta = t[i];                       // T_LIMIT = 1.0
    float s = sinf(ta * 1.5707963267948966f);
    float c = cosf(ta * 1.5707963267948966f);
    if (tid < 128) h0h[(size_t)i*384 + tid] = (_Float16)x[(size_t)i*128 + tid];
    float v = s*tW[tid] + c*tW[256+tid] + ta*tW[512+tid] + tb[tid];
    float sw = v / (1.f + __expf(-v));
    h0h[(size_t)i*384 + 128 + tid] = (_Float16)sw;
}

// ---------------- weight convert: WT[n][k] = (n<128?Wl:Wr)[k][n&127] as fp16; b2 combined
__global__ void k_cvt_w(const float* __restrict__ Wl, const float* __restrict__ Wr,
                        const float* __restrict__ bl, const float* __restrict__ br,
                        int K, _Float16* __restrict__ WT, float* __restrict__ b2) {
    int idx = blockIdx.x*256 + threadIdx.x;
    if (idx < 256) b2[idx] = (idx < 128) ? bl[idx] : br[idx-128];
    if (idx >= 256*K) return;
    int n = idx / K, k = idx - n*K;
    float v = (n < 128) ? Wl[k*128 + n] : Wr[k*128 + (n-128)];
    WT[idx] = (_Float16)v;
}

// ---------------- CSR build ----------------
__global__ void k_edge_hist(const int* __restrict__ ei, int* __restrict__ deg) {
    int e = blockIdx.x*256 + threadIdx.x;
    if (e >= E_TOT) return;
    int dst = (e < N_EDGES) ? ei[N_EDGES + e] : (e - N_EDGES);
    atomicAdd(&deg[dst], 1);
}

// batch is sorted: derive graph offsets without atomics
__global__ void k_goff(const int* __restrict__ batch, int* __restrict__ goff) {
    int i = blockIdx.x*256 + threadIdx.x;
    if (i >= N_NODES) return;
    int bi = batch[i];
    if (i == 0) {
        for (int g = 0; g <= bi; ++g) goff[g] = 0;
    } else {
        int bp = batch[i-1];
        for (int g = bp+1; g <= bi; ++g) goff[g] = i;
    }
    if (i == N_NODES-1) {
        for (int g = bi+1; g <= N_GRAPHS; ++g) goff[g] = N_NODES;
    }
}

__global__ void k_scan1(const int* __restrict__ deg, int* __restrict__ row_ptr,
                        int* __restrict__ bsums) {
    __shared__ int tmp[256];
    int tid = threadIdx.x;
    int i = blockIdx.x*256 + tid;
    int v = (i < N_NODES) ? deg[i] : 0;
    tmp[tid] = v; __syncthreads();
    for (int off = 1; off < 256; off <<= 1) {
        int tv = (tid >= off) ? tmp[tid-off] : 0;
        __syncthreads();
        tmp[tid] += tv;
        __syncthreads();
    }
    int inc = tmp[tid];
    if (i < N_NODES) row_ptr[i] = inc - v;     // block-local exclusive
    if (tid == 255) bsums[blockIdx.x] = inc;
}

__global__ void k_scan2(int* __restrict__ bsums, int nb) {
    __shared__ int tmp[256];
    int tid = threadIdx.x;
    int v = (tid < nb) ? bsums[tid] : 0;
    tmp[tid] = v; __syncthreads();
    for (int off = 1; off < 256; off <<= 1) {
        int tv = (tid >= off) ? tmp[tid-off] : 0;
        __syncthreads();
        tmp[tid] += tv;
        __syncthreads();
    }
    bsums[tid] = tmp[tid] - v;                 // exclusive over block sums
}

__global__ void k_scan3(int* __restrict__ row_ptr, const int* __restrict__ bsums,
                        int* __restrict__ cursor) {
    int i = blockIdx.x*256 + threadIdx.x;
    if (i < N_NODES) {
        int v = row_ptr[i] + bsums[blockIdx.x];
        row_ptr[i] = v;
        cursor[i] = v;
    }
    if (i == 0) row_ptr[N_NODES] = E_TOT;
}

__global__ void k_scatter(const int* __restrict__ ei, int* __restrict__ cursor,
                          int* __restrict__ csr_src) {
    int e = blockIdx.x*256 + threadIdx.x;
    if (e >= E_TOT) return;
    int src, dst;
    if (e < N_EDGES) { src = ei[e]; dst = ei[N_EDGES + e]; }
    else             { src = e - N_EDGES; dst = src; }
    int pos = atomicAdd(&cursor[dst], 1);
    csr_src[pos] = src;
}

// ---------------- dual GEMM via MFMA: [xl|xr] = A @ [Wl|Wr] + [bl|br]
// A [M,K] fp16 row-major, WT [256,K] fp16 (pre-transposed). One wave per 16
// rows; A-frags register-resident; 16 N-tiles swept with B served from L2.
// Fragment mapping (gfx950, measured): A[m=lane&15][k=quad*8+j],
// B[n=lane&15][k=quad*8+j], C/D col=lane&15 row=quad*4+reg.
template<int K>
__global__ __launch_bounds__(256) void k_gemm_mfma(
    const _Float16* __restrict__ Ah, const _Float16* __restrict__ WT,
    const float* __restrict__ b2,
    _Float16* __restrict__ xl_h, float* __restrict__ xr) {
    int wave = (blockIdx.x*256 + threadIdx.x) >> 6;
    int lane = threadIdx.x & 63;
    if (wave >= N_NODES/16) return;
    int m0 = wave * 16;
    int r16 = lane & 15, quad = lane >> 4;
    constexpr int KT = K / 32;
    half8_t afrag[KT];
    const _Float16* arow = Ah + (size_t)(m0 + r16)*K + quad*8;
    #pragma unroll
    for (int kt = 0; kt < KT; ++kt)
        afrag[kt] = *(const half8_t*)(arow + kt*32);
    #pragma unroll
    for (int nt = 0; nt < 16; ++nt) {
        floatx4 acc = {0.f, 0.f, 0.f, 0.f};
        const _Float16* brow = WT + (size_t)(nt*16 + r16)*K + quad*8;
        #pragma unroll
        for (int kt = 0; kt < KT; ++kt) {
            half8_t bfrag = *(const half8_t*)(brow + kt*32);
            acc = __builtin_amdgcn_mfma_f32_16x16x32_f16(afrag[kt], bfrag, acc, 0, 0, 0);
        }
        int col = nt*16 + r16;
        float bv = b2[col];
        if (nt < 8) {
            #pragma unroll
            for (int r = 0; r < 4; ++r)
                xl_h[(size_t)(m0 + quad*4 + r)*128 + col] = (_Float16)(acc[r] + bv);
        } else {
            #pragma unroll
            for (int r = 0; r < 4; ++r)
                xr[(size_t)(m0 + quad*4 + r)*128 + (col-128)] = acc[r] + bv;
        }
    }
}

// ---------------- GATv2 aggregation: one wave per node, online softmax.
// lane l holds channels 2l, 2l+1 (both in head l>>4). LN stats written per-node
// (plain store) — NO global atomics (sorted batch makes same-slot atomics the
// serializing bottleneck).
__global__ __launch_bounds__(256) void k_gat(
    const _Float16* __restrict__ xl_h, const float* __restrict__ xr,
    const int* __restrict__ row_ptr, const int* __restrict__ csr_src,
    const float* __restrict__ att, const float* __restrict__ bias,
    float* __restrict__ hout, float2* __restrict__ nstats) {
    int wave = (blockIdx.x * 256 + threadIdx.x) >> 6;
    int lane = threadIdx.x & 63;
    if (wave >= N_NODES) return;
    int i = wave;
    int c0 = lane * 2;
    int head = lane >> 4;
    float attv0 = att[head*32 + (c0 & 31)];
    float attv1 = att[head*32 + ((c0+1) & 31)];
    const half2_t* xlh = (const half2_t*)xl_h;
    const float2* xr2 = (const float2*)xr;
    float2 xrv = xr2[(size_t)i*64 + lane];
    int p0 = row_ptr[i], p1 = row_ptr[i+1];

    float mA = -1e30f, dA = 0.f, aA0 = 0.f, aA1 = 0.f;
    float mB = -1e30f, dB = 0.f, aB0 = 0.f, aB1 = 0.f;

    for (int p = p0; p < p1; p += 8) {
        int   idx[8];
        half2_t g[8];
        float gx[8], gy[8];
        float pt[8];
        #pragma unroll
        for (int j = 0; j < 8; ++j) {
            int pp = p + j;
            idx[j] = csr_src[(pp < p1) ? pp : (p1 - 1)];
        }
        #pragma unroll
        for (int j = 0; j < 8; ++j)
            g[j] = xlh[(size_t)idx[j]*64 + lane];
        #pragma unroll
        for (int j = 0; j < 8; ++j) { gx[j] = (float)g[j].x; gy[j] = (float)g[j].y; }
        #pragma unroll
        for (int j = 0; j < 8; ++j) {
            float m0 = gx[j] + xrv.x; m0 = (m0 >= 0.f) ? m0 : 0.2f*m0;
            float m1 = gy[j] + xrv.y; m1 = (m1 >= 0.f) ? m1 : 0.2f*m1;
            pt[j] = m0*attv0 + m1*attv1;
        }
        #pragma unroll
        for (int off = 1; off < 16; off <<= 1) {
            #pragma unroll
            for (int j = 0; j < 8; ++j) pt[j] += __shfl_xor(pt[j], off);
        }
        #pragma unroll
        for (int j = 0; j < 8; ++j)
            if (p + j >= p1) pt[j] = -1e30f;     // masked slot -> weight 0

        // chain A: slots 0..3 (always has >=1 valid edge since p < p1)
        {
            float mq = fmaxf(fmaxf(pt[0], pt[1]), fmaxf(pt[2], pt[3]));
            float w0 = __expf(pt[0]-mq), w1 = __expf(pt[1]-mq);
            float w2 = __expf(pt[2]-mq), w3 = __expf(pt[3]-mq);
            float dq  = w0 + w1 + w2 + w3;
            float aq0 = w0*gx[0] + w1*gx[1] + w2*gx[2] + w3*gx[3];
            float aq1 = w0*gy[0] + w1*gy[1] + w2*gy[2] + w3*gy[3];
            float mn = fmaxf(mA, mq);
            float sc = __expf(mA - mn), sq = __expf(mq - mn);
            dA  = dA*sc  + dq*sq;
            aA0 = aA0*sc + aq0*sq;
            aA1 = aA1*sc + aq1*sq;
            mA = mn;
        }
        // chain B: slots 4..7 (guard: quad fully masked would corrupt state)
        if (p + 4 < p1) {
            float mq = fmaxf(fmaxf(pt[4], pt[5]), fmaxf(pt[6], pt[7]));
            float w0 = __expf(pt[4]-mq), w1 = __expf(pt[5]-mq);
            float w2 = __expf(pt[6]-mq), w3 = __expf(pt[7]-mq);
            float dq  = w0 + w1 + w2 + w3;
            float aq0 = w0*gx[4] + w1*gx[5] + w2*gx[6] + w3*gx[7];
            float aq1 = w0*gy[4] + w1*gy[5] + w2*gy[6] + w3*gy[7];
            float mn = fmaxf(mB, mq);
            float sc = __expf(mB - mn), sq = __expf(mq - mn);
            dB  = dB*sc  + dq*sq;
            aB0 = aB0*sc + aq0*sq;
            aB1 = aB1*sc + aq1*sq;
            mB = mn;
        }
    }
    // merge chains (mB==-1e30 if B never ran -> sB==0)
    float mfin = fmaxf(mA, mB);
    float sA = __expf(mA - mfin), sB = __expf(mB - mfin);
    float denom = dA*sA + dB*sB;
    float acc0  = aA0*sA + aB0*sB;
    float acc1  = aA1*sA + aB1*sB;

    float inv = 1.f / (denom + 1e-16f);
    float v0 = acc0 * inv + bias[c0];
    float v1 = acc1 * inv + bias[c0+1];
    hout[(size_t)i*128 + c0]     = v0;
    hout[(size_t)i*128 + c0 + 1] = v1;
    // per-node LN statistics (reduced per-graph by k_graph_red, no atomics)
    float s1 = v0 + v1;
    float s2 = v0*v0 + v1*v1;
    #pragma unroll
    for (int off = 1; off < 64; off <<= 1) {
        s1 += __shfl_xor(s1, off);
        s2 += __shfl_xor(s2, off);
    }
    if (lane == 0) nstats[i] = make_float2(s1, s2);
}

// ---------------- per-graph reduction of node stats (plain stores) ----------
__global__ __launch_bounds__(256) void k_graph_red(
    const float2* __restrict__ nstats, const int* __restrict__ goff,
    float* __restrict__ gsum, float* __restrict__ gsumsq) {
    __shared__ float l1[256], l2[256];
    int g = blockIdx.x;
    int tid = threadIdx.x;
    int a = goff[g], b = goff[g+1];
    float s1 = 0.f, s2 = 0.f;
    for (int i = a + tid; i < b; i += 256) {
        float2 v = nstats[i];
        s1 += v.x; s2 += v.y;
    }
    l1[tid] = s1; l2[tid] = s2; __syncthreads();
    for (int off = 128; off > 0; off >>= 1) {
        if (tid < off) { l1[tid] += l1[tid+off]; l2[tid] += l2[tid+off]; }
        __syncthreads();
    }
    if (tid == 0) { gsum[g] = l1[0]; gsumsq[g] = l2[0]; }
}

// ---------------- graph layernorm apply (fp16 out; consumed by MFMA GEMM,
// gathers, and pair scoring) ----------
__global__ void k_ln(const float* __restrict__ hout, const int* __restrict__ batch,
                     const int* __restrict__ goff, const float* __restrict__ gsum,
                     const float* __restrict__ gsumsq, const float* __restrict__ w,
                     const float* __restrict__ b, _Float16* __restrict__ hb) {
    int idx = blockIdx.x*256 + threadIdx.x;
    if (idx >= N_NODES*128) return;
    int i = idx >> 7, c = idx & 127;
    int g = batch[i];
    float cnt = (float)(goff[g+1] - goff[g]) * 128.f;
    cnt = fmaxf(cnt, 1.f);
    float mean = gsum[g] / cnt;
    float var = gsumsq[g] / cnt - mean*mean;
    var = fmaxf(var, 0.f);
    float rstd = rsqrtf(var + 1e-5f);
    float v = (hout[idx] - mean) * rstd * w[c] + b[c];
    hb[idx] = (_Float16)v;
}

// ---------------- pair scoring: 32 lanes per pair, fp16 gathers ----------------
__global__ __launch_bounds__(256) void k_pairs(
    const _Float16* __restrict__ hb, const int* __restrict__ pi,
    const float* __restrict__ lW, const float* __restrict__ lb,
    float* __restrict__ out) {
    int grp = (blockIdx.x*256 + threadIdx.x) >> 5;
    int q = threadIdx.x & 31;
    if (grp >= N_PAIRS) return;
    int p0 = pi[grp], p1 = pi[N_PAIRS + grp];
    const half4_t* h4 = (const half4_t*)hb;
    const float4* w4 = (const float4*)lW;
    half4_t a = h4[(size_t)p0*32 + q];
    half4_t b = h4[(size_t)p1*32 + q];
    float4 w = w4[q];
    float part = (float)a.x*(float)b.x*w.x + (float)a.y*(float)b.y*w.y
               + (float)a.z*(float)b.z*w.z + (float)a.w*(float)b.w*w.w;
    part += __shfl_xor(part, 1);
    part += __shfl_xor(part, 2);
    part += __shfl_xor(part, 4);
    part += __shfl_xor(part, 8);
    part += __shfl_xor(part, 16);
    if (q == 0) out[grp] = 1.f / (1.f + __expf(-(part + lb[0])));
}

extern "C" void kernel_launch(void* const* d_in, const int* in_sizes, int n_in,
                              void* d_out, int out_size, void* d_ws, size_t ws_size,
                              hipStream_t stream) {
    const float* x     = (const float*)d_in[0];
    const float* t     = (const float*)d_in[1];
    const int*   ei    = (const int*)  d_in[2];
    const int*   pi    = (const int*)  d_in[3];
    const int*   batch = (const int*)  d_in[4];
    const float* tW    = (const float*)d_in[5];
    const float* tb    = (const float*)d_in[6];
    const float* W0l   = (const float*)d_in[7];
    const float* b0l   = (const float*)d_in[8];
    const float* W0r   = (const float*)d_in[9];
    const float* b0r   = (const float*)d_in[10];
    const float* att0  = (const float*)d_in[11];
    const float* bias0 = (const float*)d_in[12];
    const float* Wl    = (const float*)d_in[13];
    const float* bl    = (const float*)d_in[14];
    const float* Wr    = (const float*)d_in[15];
    const float* br    = (const float*)d_in[16];
    const float* att   = (const float*)d_in[17];
    const float* bias  = (const float*)d_in[18];
    const float* lnw   = (const float*)d_in[19];
    const float* lnb   = (const float*)d_in[20];
    const float* lW    = (const float*)d_in[21];
    const float* lb    = (const float*)d_in[22];
    float* out = (float*)d_out;

    char* ws = (char*)d_ws;
    size_t off = 0;
    auto walloc = [&](size_t bytes) -> void* {
        void* p = ws + off;
        off += (bytes + 255) & ~(size_t)255;
        return p;
    };
    _Float16*  h0h     = (_Float16*) walloc((size_t)N_NODES*384*2);
    float*     hout    = (float*)    walloc((size_t)N_NODES*128*4);
    _Float16*  xl_h    = (_Float16*) walloc((size_t)N_NODES*128*2);
    float*     xr      = (float*)    walloc((size_t)N_NODES*128*4);
    _Float16*  hb      = (_Float16*) walloc((size_t)N_NODES*128*2);
    int*       deg     = (int*)      walloc((size_t)N_NODES*4);   // reused as cursor
    int*       row_ptr = (int*)      walloc((size_t)(N_NODES+1)*4);
    int*       csr_src = (int*)      walloc((size_t)E_TOT*4);
    int*       bsums   = (int*)      walloc(256*4);
    int*       goff    = (int*)      walloc(64*4);
    float2*    nstats  = (float2*)   walloc((size_t)N_NODES*8);
    float*     stats   = (float*)    walloc(2*64*4);              // [sum|sumsq][64]
    _Float16*  WT0     = (_Float16*) walloc(256*384*2);
    _Float16*  WT123   = (_Float16*) walloc(3*256*128*2);
    float*     b2      = (float*)    walloc(4*256*4);

    hipMemsetAsync(deg, 0, (size_t)N_NODES*4, stream);

    k_time_embed<<<N_NODES, 256, 0, stream>>>(x, t, tW, tb, h0h);
    k_cvt_w<<<(256*384+255)/256, 256, 0, stream>>>(W0l, W0r, b0l, b0r, 384, WT0, b2);
    for (int l = 0; l < 3; ++l)
        k_cvt_w<<<(256*128+255)/256, 256, 0, stream>>>(
            Wl + (size_t)l*128*128, Wr + (size_t)l*128*128,
            bl + l*128, br + l*128, 128, WT123 + (size_t)l*256*128, b2 + (l+1)*256);
    k_edge_hist<<<(E_TOT+255)/256, 256, 0, stream>>>(ei, deg);
    k_goff<<<SCAN_NB, 256, 0, stream>>>(batch, goff);
    k_scan1<<<SCAN_NB, 256, 0, stream>>>(deg, row_ptr, bsums);
    k_scan2<<<1, 256, 0, stream>>>(bsums, SCAN_NB);
    k_scan3<<<SCAN_NB, 256, 0, stream>>>(row_ptr, bsums, deg);   // deg becomes cursor
    k_scatter<<<(E_TOT+255)/256, 256, 0, stream>>>(ei, deg, csr_src);

    float* gsum   = stats;
    float* gsumsq = stats + 64;
    const int GEMM_BLOCKS = (N_NODES/16 + 3) / 4;   // 4 waves/block, 16 rows/wave
    for (int L = 0; L < 4; ++L) {
        if (L == 0)
            k_gemm_mfma<384><<<GEMM_BLOCKS, 256, 0, stream>>>(h0h, WT0, b2, xl_h, xr);
        else
            k_gemm_mfma<128><<<GEMM_BLOCKS, 256, 0, stream>>>(
                hb, WT123 + (size_t)(L-1)*256*128, b2 + L*256, xl_h, xr);
        const float* attL  = (L == 0) ? att0  : att  + (size_t)(L-1)*128;
        const float* biasL = (L == 0) ? bias0 : bias + (size_t)(L-1)*128;
        k_gat<<<N_NODES/4, 256, 0, stream>>>(xl_h, xr, row_ptr, csr_src, attL, biasL,
                                             hout, nstats);
        k_graph_red<<<N_GRAPHS, 256, 0, stream>>>(nstats, goff, gsum, gsumsq);
        k_ln<<<(N_NODES*128+255)/256, 256, 0, stream>>>(hout, batch, goff, gsum, gsumsq,
                                                        lnw + L*128, lnb + L*128, hb);
    }

    k_pairs<<<((size_t)N_PAIRS*32 + 255)/256, 256, 0, stream>>>(hb, pi, lW, lb, out);
}

// Round 6
// 1256.577 us; speedup vs baseline: 2.8394x; 1.0862x over previous
//
#include <hip/hip_runtime.h>
#include <hip/hip_bf16.h>
#include <hip/hip_fp16.h>

#define N_NODES 50000
#define N_EDGES 1600000
#define E_TOT   1650000   // N_EDGES + N_NODES self loops
#define N_PAIRS 2000000
#define N_GRAPHS 50
#define SCAN_NB 196       // ceil(N_NODES/256)

typedef __attribute__((ext_vector_type(2))) _Float16 half2_t;
typedef __attribute__((ext_vector_type(4))) _Float16 half4_t;
typedef __attribute__((ext_vector_type(8))) _Float16 half8_t;
typedef __attribute__((ext_vector_type(4))) float floatx4;

// ---------------- time embedding: h0h[:, :128]=x, h0h[:,128:384]=swish(...) (fp16 out)
__global__ void k_time_embed(const float* __restrict__ x, const float* __restrict__ t,
                             const float* __restrict__ tW, const float* __restrict__ tb,
                             _Float16* __restrict__ h0h) {
    int i = blockIdx.x;
    int tid = threadIdx.x;
    float ta = t[i];                       // T_LIMIT = 1.0
    float s = sinf(ta * 1.5707963267948966f);
    float c = cosf(ta * 1.5707963267948966f);
    if (tid < 128) h0h[(size_t)i*384 + tid] = (_Float16)x[(size_t)i*128 + tid];
    float v = s*tW[tid] + c*tW[256+tid] + ta*tW[512+tid] + tb[tid];
    float sw = v / (1.f + __expf(-v));
    h0h[(size_t)i*384 + 128 + tid] = (_Float16)sw;
}

// ---------------- weight convert: WT[n][k] = (n<128?Wl:Wr)[k][n&127] as fp16; b2 combined
__global__ void k_cvt_w(const float* __restrict__ Wl, const float* __restrict__ Wr,
                        const float* __restrict__ bl, const float* __restrict__ br,
                        int K, _Float16* __restrict__ WT, float* __restrict__ b2) {
    int idx = blockIdx.x*256 + threadIdx.x;
    if (idx < 256) b2[idx] = (idx < 128) ? bl[idx] : br[idx-128];
    if (idx >= 256*K) return;
    int n = idx / K, k = idx - n*K;
    float v = (n < 128) ? Wl[k*128 + n] : Wr[k*128 + (n-128)];
    WT[idx] = (_Float16)v;
}

// ---------------- CSR build ----------------
__global__ void k_edge_hist(const int* __restrict__ ei, int* __restrict__ deg) {
    int e = blockIdx.x*256 + threadIdx.x;
    if (e >= E_TOT) return;
    int dst = (e < N_EDGES) ? ei[N_EDGES + e] : (e - N_EDGES);
    atomicAdd(&deg[dst], 1);
}

// batch is sorted: derive graph offsets without atomics
__global__ void k_goff(const int* __restrict__ batch, int* __restrict__ goff) {
    int i = blockIdx.x*256 + threadIdx.x;
    if (i >= N_NODES) return;
    int bi = batch[i];
    if (i == 0) {
        for (int g = 0; g <= bi; ++g) goff[g] = 0;
    } else {
        int bp = batch[i-1];
        for (int g = bp+1; g <= bi; ++g) goff[g] = i;
    }
    if (i == N_NODES-1) {
        for (int g = bi+1; g <= N_GRAPHS; ++g) goff[g] = N_NODES;
    }
}

__global__ void k_scan1(const int* __restrict__ deg, int* __restrict__ row_ptr,
                        int* __restrict__ bsums) {
    __shared__ int tmp[256];
    int tid = threadIdx.x;
    int i = blockIdx.x*256 + tid;
    int v = (i < N_NODES) ? deg[i] : 0;
    tmp[tid] = v; __syncthreads();
    for (int off = 1; off < 256; off <<= 1) {
        int tv = (tid >= off) ? tmp[tid-off] : 0;
        __syncthreads();
        tmp[tid] += tv;
        __syncthreads();
    }
    int inc = tmp[tid];
    if (i < N_NODES) row_ptr[i] = inc - v;     // block-local exclusive
    if (tid == 255) bsums[blockIdx.x] = inc;
}

__global__ void k_scan2(int* __restrict__ bsums, int nb) {
    __shared__ int tmp[256];
    int tid = threadIdx.x;
    int v = (tid < nb) ? bsums[tid] : 0;
    tmp[tid] = v; __syncthreads();
    for (int off = 1; off < 256; off <<= 1) {
        int tv = (tid >= off) ? tmp[tid-off] : 0;
        __syncthreads();
        tmp[tid] += tv;
        __syncthreads();
    }
    bsums[tid] = tmp[tid] - v;                 // exclusive over block sums
}

__global__ void k_scan3(int* __restrict__ row_ptr, const int* __restrict__ bsums,
                        int* __restrict__ cursor) {
    int i = blockIdx.x*256 + threadIdx.x;
    if (i < N_NODES) {
        int v = row_ptr[i] + bsums[blockIdx.x];
        row_ptr[i] = v;
        cursor[i] = v;
    }
    if (i == 0) row_ptr[N_NODES] = E_TOT;
}

__global__ void k_scatter(const int* __restrict__ ei, int* __restrict__ cursor,
                          int* __restrict__ csr_src) {
    int e = blockIdx.x*256 + threadIdx.x;
    if (e >= E_TOT) return;
    int src, dst;
    if (e < N_EDGES) { src = ei[e]; dst = ei[N_EDGES + e]; }
    else             { src = e - N_EDGES; dst = src; }
    int pos = atomicAdd(&cursor[dst], 1);
    csr_src[pos] = src;
}

// ---------------- dual GEMM via MFMA: [xl|xr] = A @ [Wl|Wr] + [bl|br]
// A [M,K] fp16 row-major, WT [256,K] fp16 (pre-transposed). One wave per 16
// rows; A-frags register-resident; 16 N-tiles swept with B served from L2.
template<int K>
__global__ __launch_bounds__(256) void k_gemm_mfma(
    const _Float16* __restrict__ Ah, const _Float16* __restrict__ WT,
    const float* __restrict__ b2,
    _Float16* __restrict__ xl_h, float* __restrict__ xr) {
    int wave = (blockIdx.x*256 + threadIdx.x) >> 6;
    int lane = threadIdx.x & 63;
    if (wave >= N_NODES/16) return;
    int m0 = wave * 16;
    int r16 = lane & 15, quad = lane >> 4;
    constexpr int KT = K / 32;
    half8_t afrag[KT];
    const _Float16* arow = Ah + (size_t)(m0 + r16)*K + quad*8;
    #pragma unroll
    for (int kt = 0; kt < KT; ++kt)
        afrag[kt] = *(const half8_t*)(arow + kt*32);
    #pragma unroll
    for (int nt = 0; nt < 16; ++nt) {
        floatx4 acc = {0.f, 0.f, 0.f, 0.f};
        const _Float16* brow = WT + (size_t)(nt*16 + r16)*K + quad*8;
        #pragma unroll
        for (int kt = 0; kt < KT; ++kt) {
            half8_t bfrag = *(const half8_t*)(brow + kt*32);
            acc = __builtin_amdgcn_mfma_f32_16x16x32_f16(afrag[kt], bfrag, acc, 0, 0, 0);
        }
        int col = nt*16 + r16;
        float bv = b2[col];
        if (nt < 8) {
            #pragma unroll
            for (int r = 0; r < 4; ++r)
                xl_h[(size_t)(m0 + quad*4 + r)*128 + col] = (_Float16)(acc[r] + bv);
        } else {
            #pragma unroll
            for (int r = 0; r < 4; ++r)
                xr[(size_t)(m0 + quad*4 + r)*128 + (col-128)] = acc[r] + bv;
        }
    }
}

// ---------------- GATv2 aggregation: one wave per node, online softmax.
__global__ __launch_bounds__(256) void k_gat(
    const _Float16* __restrict__ xl_h, const float* __restrict__ xr,
    const int* __restrict__ row_ptr, const int* __restrict__ csr_src,
    const float* __restrict__ att, const float* __restrict__ bias,
    float* __restrict__ hout, float2* __restrict__ nstats) {
    int wave = (blockIdx.x * 256 + threadIdx.x) >> 6;
    int lane = threadIdx.x & 63;
    if (wave >= N_NODES) return;
    int i = wave;
    int c0 = lane * 2;
    int head = lane >> 4;
    float attv0 = att[head*32 + (c0 & 31)];
    float attv1 = att[head*32 + ((c0+1) & 31)];
    const half2_t* xlh = (const half2_t*)xl_h;
    const float2* xr2 = (const float2*)xr;
    float2 xrv = xr2[(size_t)i*64 + lane];
    int p0 = row_ptr[i], p1 = row_ptr[i+1];

    float mA = -1e30f, dA = 0.f, aA0 = 0.f, aA1 = 0.f;
    float mB = -1e30f, dB = 0.f, aB0 = 0.f, aB1 = 0.f;

    for (int p = p0; p < p1; p += 8) {
        int   idx[8];
        half2_t g[8];
        float gx[8], gy[8];
        float pt[8];
        #pragma unroll
        for (int j = 0; j < 8; ++j) {
            int pp = p + j;
            idx[j] = csr_src[(pp < p1) ? pp : (p1 - 1)];
        }
        #pragma unroll
        for (int j = 0; j < 8; ++j)
            g[j] = xlh[(size_t)idx[j]*64 + lane];
        #pragma unroll
        for (int j = 0; j < 8; ++j) { gx[j] = (float)g[j].x; gy[j] = (float)g[j].y; }
        #pragma unroll
        for (int j = 0; j < 8; ++j) {
            float m0 = gx[j] + xrv.x; m0 = (m0 >= 0.f) ? m0 : 0.2f*m0;
            float m1 = gy[j] + xrv.y; m1 = (m1 >= 0.f) ? m1 : 0.2f*m1;
            pt[j] = m0*attv0 + m1*attv1;
        }
        #pragma unroll
        for (int off = 1; off < 16; off <<= 1) {
            #pragma unroll
            for (int j = 0; j < 8; ++j) pt[j] += __shfl_xor(pt[j], off);
        }
        #pragma unroll
        for (int j = 0; j < 8; ++j)
            if (p + j >= p1) pt[j] = -1e30f;     // masked slot -> weight 0

        // chain A: slots 0..3 (always has >=1 valid edge since p < p1)
        {
            float mq = fmaxf(fmaxf(pt[0], pt[1]), fmaxf(pt[2], pt[3]));
            float w0 = __expf(pt[0]-mq), w1 = __expf(pt[1]-mq);
            float w2 = __expf(pt[2]-mq), w3 = __expf(pt[3]-mq);
            float dq  = w0 + w1 + w2 + w3;
            float aq0 = w0*gx[0] + w1*gx[1] + w2*gx[2] + w3*gx[3];
            float aq1 = w0*gy[0] + w1*gy[1] + w2*gy[2] + w3*gy[3];
            float mn = fmaxf(mA, mq);
            float sc = __expf(mA - mn), sq = __expf(mq - mn);
            dA  = dA*sc  + dq*sq;
            aA0 = aA0*sc + aq0*sq;
            aA1 = aA1*sc + aq1*sq;
            mA = mn;
        }
        // chain B: slots 4..7 (guard: quad fully masked would corrupt state)
        if (p + 4 < p1) {
            float mq = fmaxf(fmaxf(pt[4], pt[5]), fmaxf(pt[6], pt[7]));
            float w0 = __expf(pt[4]-mq), w1 = __expf(pt[5]-mq);
            float w2 = __expf(pt[6]-mq), w3 = __expf(pt[7]-mq);
            float dq  = w0 + w1 + w2 + w3;
            float aq0 = w0*gx[4] + w1*gx[5] + w2*gx[6] + w3*gx[7];
            float aq1 = w0*gy[4] + w1*gy[5] + w2*gy[6] + w3*gy[7];
            float mn = fmaxf(mB, mq);
            float sc = __expf(mB - mn), sq = __expf(mq - mn);
            dB  = dB*sc  + dq*sq;
            aB0 = aB0*sc + aq0*sq;
            aB1 = aB1*sc + aq1*sq;
            mB = mn;
        }
    }
    // merge chains (mB==-1e30 if B never ran -> sB==0)
    float mfin = fmaxf(mA, mB);
    float sA = __expf(mA - mfin), sB = __expf(mB - mfin);
    float denom = dA*sA + dB*sB;
    float acc0  = aA0*sA + aB0*sB;
    float acc1  = aA1*sA + aB1*sB;

    float inv = 1.f / (denom + 1e-16f);
    float v0 = acc0 * inv + bias[c0];
    float v1 = acc1 * inv + bias[c0+1];
    hout[(size_t)i*128 + c0]     = v0;
    hout[(size_t)i*128 + c0 + 1] = v1;
    // per-node LN statistics (reduced per-graph by k_graph_red, no atomics)
    float s1 = v0 + v1;
    float s2 = v0*v0 + v1*v1;
    #pragma unroll
    for (int off = 1; off < 64; off <<= 1) {
        s1 += __shfl_xor(s1, off);
        s2 += __shfl_xor(s2, off);
    }
    if (lane == 0) nstats[i] = make_float2(s1, s2);
}

// ---------------- per-graph reduction of node stats (plain stores) ----------
__global__ __launch_bounds__(256) void k_graph_red(
    const float2* __restrict__ nstats, const int* __restrict__ goff,
    float* __restrict__ gsum, float* __restrict__ gsumsq) {
    __shared__ float l1[256], l2[256];
    int g = blockIdx.x;
    int tid = threadIdx.x;
    int a = goff[g], b = goff[g+1];
    float s1 = 0.f, s2 = 0.f;
    for (int i = a + tid; i < b; i += 256) {
        float2 v = nstats[i];
        s1 += v.x; s2 += v.y;
    }
    l1[tid] = s1; l2[tid] = s2; __syncthreads();
    for (int off = 128; off > 0; off >>= 1) {
        if (tid < off) { l1[tid] += l1[tid+off]; l2[tid] += l2[tid+off]; }
        __syncthreads();
    }
    if (tid == 0) { gsum[g] = l1[0]; gsumsq[g] = l2[0]; }
}

// ---------------- graph layernorm apply (fp16 out). For the last layer also
// writes hbw = h * link_W (w-folded copy used by k_pairs' fdot2 path). ----------
__global__ void k_ln(const float* __restrict__ hout, const int* __restrict__ batch,
                     const int* __restrict__ goff, const float* __restrict__ gsum,
                     const float* __restrict__ gsumsq, const float* __restrict__ w,
                     const float* __restrict__ b, _Float16* __restrict__ hb,
                     const float* __restrict__ linkW, _Float16* __restrict__ hbw) {
    int idx = blockIdx.x*256 + threadIdx.x;
    if (idx >= N_NODES*128) return;
    int i = idx >> 7, c = idx & 127;
    int g = batch[i];
    float cnt = (float)(goff[g+1] - goff[g]) * 128.f;
    cnt = fmaxf(cnt, 1.f);
    float mean = gsum[g] / cnt;
    float var = gsumsq[g] / cnt - mean*mean;
    var = fmaxf(var, 0.f);
    float rstd = rsqrtf(var + 1e-5f);
    float v = (hout[idx] - mean) * rstd * w[c] + b[c];
    hb[idx] = (_Float16)v;
    if (hbw) hbw[idx] = (_Float16)(v * linkW[c]);
}

// ---------------- pair scoring: 16 lanes/pair, fp16 half8 loads, fdot2 ------
__global__ __launch_bounds__(256) void k_pairs(
    const _Float16* __restrict__ hbw, const _Float16* __restrict__ hb,
    const int* __restrict__ pi, const float* __restrict__ lb,
    float* __restrict__ out) {
    int grp = (blockIdx.x*256 + threadIdx.x) >> 4;
    int q = threadIdx.x & 15;
    if (grp >= N_PAIRS) return;
    int p0 = pi[grp], p1 = pi[N_PAIRS + grp];
    const half8_t* A = (const half8_t*)hbw;
    const half8_t* B = (const half8_t*)hb;
    half8_t a = A[(size_t)p0*16 + q];
    half8_t b = B[(size_t)p1*16 + q];
    const half2_t* a2 = (const half2_t*)&a;
    const half2_t* b2 = (const half2_t*)&b;
    float part = 0.f;
    #pragma unroll
    for (int j = 0; j < 4; ++j)
        part = __builtin_amdgcn_fdot2(a2[j], b2[j], part, false);
    part += __shfl_xor(part, 1);
    part += __shfl_xor(part, 2);
    part += __shfl_xor(part, 4);
    part += __shfl_xor(part, 8);
    if (q == 0) out[grp] = 1.f / (1.f + __expf(-(part + lb[0])));
}

extern "C" void kernel_launch(void* const* d_in, const int* in_sizes, int n_in,
                              void* d_out, int out_size, void* d_ws, size_t ws_size,
                              hipStream_t stream) {
    const float* x     = (const float*)d_in[0];
    const float* t     = (const float*)d_in[1];
    const int*   ei    = (const int*)  d_in[2];
    const int*   pi    = (const int*)  d_in[3];
    const int*   batch = (const int*)  d_in[4];
    const float* tW    = (const float*)d_in[5];
    const float* tb    = (const float*)d_in[6];
    const float* W0l   = (const float*)d_in[7];
    const float* b0l   = (const float*)d_in[8];
    const float* W0r   = (const float*)d_in[9];
    const float* b0r   = (const float*)d_in[10];
    const float* att0  = (const float*)d_in[11];
    const float* bias0 = (const float*)d_in[12];
    const float* Wl    = (const float*)d_in[13];
    const float* bl    = (const float*)d_in[14];
    const float* Wr    = (const float*)d_in[15];
    const float* br    = (const float*)d_in[16];
    const float* att   = (const float*)d_in[17];
    const float* bias  = (const float*)d_in[18];
    const float* lnw   = (const float*)d_in[19];
    const float* lnb   = (const float*)d_in[20];
    const float* lW    = (const float*)d_in[21];
    const float* lb    = (const float*)d_in[22];
    float* out = (float*)d_out;

    char* ws = (char*)d_ws;
    size_t off = 0;
    auto walloc = [&](size_t bytes) -> void* {
        void* p = ws + off;
        off += (bytes + 255) & ~(size_t)255;
        return p;
    };
    _Float16*  h0h     = (_Float16*) walloc((size_t)N_NODES*384*2);
    float*     hout    = (float*)    walloc((size_t)N_NODES*128*4);
    _Float16*  xl_h    = (_Float16*) walloc((size_t)N_NODES*128*2);
    float*     xr      = (float*)    walloc((size_t)N_NODES*128*4);
    _Float16*  hb      = (_Float16*) walloc((size_t)N_NODES*128*2);
    _Float16*  hbw     = (_Float16*) walloc((size_t)N_NODES*128*2);
    int*       deg     = (int*)      walloc((size_t)N_NODES*4);   // reused as cursor
    int*       row_ptr = (int*)      walloc((size_t)(N_NODES+1)*4);
    int*       csr_src = (int*)      walloc((size_t)E_TOT*4);
    int*       bsums   = (int*)      walloc(256*4);
    int*       goff    = (int*)      walloc(64*4);
    float2*    nstats  = (float2*)   walloc((size_t)N_NODES*8);
    float*     stats   = (float*)    walloc(2*64*4);              // [sum|sumsq][64]
    _Float16*  WT0     = (_Float16*) walloc(256*384*2);
    _Float16*  WT123   = (_Float16*) walloc(3*256*128*2);
    float*     b2      = (float*)    walloc(4*256*4);

    hipMemsetAsync(deg, 0, (size_t)N_NODES*4, stream);

    k_time_embed<<<N_NODES, 256, 0, stream>>>(x, t, tW, tb, h0h);
    k_cvt_w<<<(256*384+255)/256, 256, 0, stream>>>(W0l, W0r, b0l, b0r, 384, WT0, b2);
    for (int l = 0; l < 3; ++l)
        k_cvt_w<<<(256*128+255)/256, 256, 0, stream>>>(
            Wl + (size_t)l*128*128, Wr + (size_t)l*128*128,
            bl + l*128, br + l*128, 128, WT123 + (size_t)l*256*128, b2 + (l+1)*256);
    k_edge_hist<<<(E_TOT+255)/256, 256, 0, stream>>>(ei, deg);
    k_goff<<<SCAN_NB, 256, 0, stream>>>(batch, goff);
    k_scan1<<<SCAN_NB, 256, 0, stream>>>(deg, row_ptr, bsums);
    k_scan2<<<1, 256, 0, stream>>>(bsums, SCAN_NB);
    k_scan3<<<SCAN_NB, 256, 0, stream>>>(row_ptr, bsums, deg);   // deg becomes cursor
    k_scatter<<<(E_TOT+255)/256, 256, 0, stream>>>(ei, deg, csr_src);

    float* gsum   = stats;
    float* gsumsq = stats + 64;
    const int GEMM_BLOCKS = (N_NODES/16 + 3) / 4;   // 4 waves/block, 16 rows/wave
    for (int L = 0; L < 4; ++L) {
        if (L == 0)
            k_gemm_mfma<384><<<GEMM_BLOCKS, 256, 0, stream>>>(h0h, WT0, b2, xl_h, xr);
        else
            k_gemm_mfma<128><<<GEMM_BLOCKS, 256, 0, stream>>>(
                hb, WT123 + (size_t)(L-1)*256*128, b2 + L*256, xl_h, xr);
        const float* attL  = (L == 0) ? att0  : att  + (size_t)(L-1)*128;
        const float* biasL = (L == 0) ? bias0 : bias + (size_t)(L-1)*128;
        k_gat<<<N_NODES/4, 256, 0, stream>>>(xl_h, xr, row_ptr, csr_src, attL, biasL,
                                             hout, nstats);
        k_graph_red<<<N_GRAPHS, 256, 0, stream>>>(nstats, goff, gsum, gsumsq);
        k_ln<<<(N_NODES*128+255)/256, 256, 0, stream>>>(
            hout, batch, goff, gsum, gsumsq, lnw + L*128, lnb + L*128, hb,
            lW, (L == 3) ? hbw : (_Float16*)nullptr);
    }

    k_pairs<<<((size_t)N_PAIRS*16 + 255)/256, 256, 0, stream>>>(hbw, hb, pi, lb, out);
}

// Round 7
// 1062.829 us; speedup vs baseline: 3.3571x; 1.1823x over previous
//
#include <hip/hip_runtime.h>
#include <hip/hip_bf16.h>
#include <hip/hip_fp16.h>

#define N_NODES 50000
#define N_EDGES 1600000
#define E_TOT   1650000   // N_EDGES + N_NODES self loops
#define N_PAIRS 2000000
#define N_GRAPHS 50
#define SCAN_NB 196       // ceil(N_NODES/256)

typedef __attribute__((ext_vector_type(2))) _Float16 half2_t;
typedef __attribute__((ext_vector_type(4))) _Float16 half4_t;
typedef __attribute__((ext_vector_type(8))) _Float16 half8_t;
typedef __attribute__((ext_vector_type(4))) float floatx4;

// ---------------- time embedding: h0h[:, :128]=x, h0h[:,128:384]=swish(...) (fp16 out)
__global__ void k_time_embed(const float* __restrict__ x, const float* __restrict__ t,
                             const float* __restrict__ tW, const float* __restrict__ tb,
                             _Float16* __restrict__ h0h) {
    int i = blockIdx.x;
    int tid = threadIdx.x;
    float ta = t[i];                       // T_LIMIT = 1.0
    float s = sinf(ta * 1.5707963267948966f);
    float c = cosf(ta * 1.5707963267948966f);
    if (tid < 128) h0h[(size_t)i*384 + tid] = (_Float16)x[(size_t)i*128 + tid];
    float v = s*tW[tid] + c*tW[256+tid] + ta*tW[512+tid] + tb[tid];
    float sw = v / (1.f + __expf(-v));
    h0h[(size_t)i*384 + 128 + tid] = (_Float16)sw;
}

// ---------------- weight convert: WT[n][k] = (n<128?Wl:Wr)[k][n&127] as fp16; b2 combined
__global__ void k_cvt_w(const float* __restrict__ Wl, const float* __restrict__ Wr,
                        const float* __restrict__ bl, const float* __restrict__ br,
                        int K, _Float16* __restrict__ WT, float* __restrict__ b2) {
    int idx = blockIdx.x*256 + threadIdx.x;
    if (idx < 256) b2[idx] = (idx < 128) ? bl[idx] : br[idx-128];
    if (idx >= 256*K) return;
    int n = idx / K, k = idx - n*K;
    float v = (n < 128) ? Wl[k*128 + n] : Wr[k*128 + (n-128)];
    WT[idx] = (_Float16)v;
}

// ---------------- CSR build ----------------
__global__ void k_edge_hist(const int* __restrict__ ei, int* __restrict__ deg) {
    int e = blockIdx.x*256 + threadIdx.x;
    if (e >= E_TOT) return;
    int dst = (e < N_EDGES) ? ei[N_EDGES + e] : (e - N_EDGES);
    atomicAdd(&deg[dst], 1);
}

// batch is sorted: derive graph offsets without atomics
__global__ void k_goff(const int* __restrict__ batch, int* __restrict__ goff) {
    int i = blockIdx.x*256 + threadIdx.x;
    if (i >= N_NODES) return;
    int bi = batch[i];
    if (i == 0) {
        for (int g = 0; g <= bi; ++g) goff[g] = 0;
    } else {
        int bp = batch[i-1];
        for (int g = bp+1; g <= bi; ++g) goff[g] = i;
    }
    if (i == N_NODES-1) {
        for (int g = bi+1; g <= N_GRAPHS; ++g) goff[g] = N_NODES;
    }
}

__global__ void k_scan1(const int* __restrict__ deg, int* __restrict__ row_ptr,
                        int* __restrict__ bsums) {
    __shared__ int tmp[256];
    int tid = threadIdx.x;
    int i = blockIdx.x*256 + tid;
    int v = (i < N_NODES) ? deg[i] : 0;
    tmp[tid] = v; __syncthreads();
    for (int off = 1; off < 256; off <<= 1) {
        int tv = (tid >= off) ? tmp[tid-off] : 0;
        __syncthreads();
        tmp[tid] += tv;
        __syncthreads();
    }
    int inc = tmp[tid];
    if (i < N_NODES) row_ptr[i] = inc - v;     // block-local exclusive
    if (tid == 255) bsums[blockIdx.x] = inc;
}

__global__ void k_scan2(int* __restrict__ bsums, int nb) {
    __shared__ int tmp[256];
    int tid = threadIdx.x;
    int v = (tid < nb) ? bsums[tid] : 0;
    tmp[tid] = v; __syncthreads();
    for (int off = 1; off < 256; off <<= 1) {
        int tv = (tid >= off) ? tmp[tid-off] : 0;
        __syncthreads();
        tmp[tid] += tv;
        __syncthreads();
    }
    bsums[tid] = tmp[tid] - v;                 // exclusive over block sums
}

__global__ void k_scan3(int* __restrict__ row_ptr, const int* __restrict__ bsums,
                        int* __restrict__ cursor) {
    int i = blockIdx.x*256 + threadIdx.x;
    if (i < N_NODES) {
        int v = row_ptr[i] + bsums[blockIdx.x];
        row_ptr[i] = v;
        cursor[i] = v;
    }
    if (i == 0) row_ptr[N_NODES] = E_TOT;
}

__global__ void k_scatter(const int* __restrict__ ei, int* __restrict__ cursor,
                          int* __restrict__ csr_src) {
    int e = blockIdx.x*256 + threadIdx.x;
    if (e >= E_TOT) return;
    int src, dst;
    if (e < N_EDGES) { src = ei[e]; dst = ei[N_EDGES + e]; }
    else             { src = e - N_EDGES; dst = src; }
    int pos = atomicAdd(&cursor[dst], 1);
    csr_src[pos] = src;
}

// ---------------- dual GEMM via MFMA: [xl|xr] = A @ [Wl|Wr] + [bl|br]
template<int K>
__global__ __launch_bounds__(256) void k_gemm_mfma(
    const _Float16* __restrict__ Ah, const _Float16* __restrict__ WT,
    const float* __restrict__ b2,
    _Float16* __restrict__ xl_h, float* __restrict__ xr) {
    int wave = (blockIdx.x*256 + threadIdx.x) >> 6;
    int lane = threadIdx.x & 63;
    if (wave >= N_NODES/16) return;
    int m0 = wave * 16;
    int r16 = lane & 15, quad = lane >> 4;
    constexpr int KT = K / 32;
    half8_t afrag[KT];
    const _Float16* arow = Ah + (size_t)(m0 + r16)*K + quad*8;
    #pragma unroll
    for (int kt = 0; kt < KT; ++kt)
        afrag[kt] = *(const half8_t*)(arow + kt*32);
    #pragma unroll
    for (int nt = 0; nt < 16; ++nt) {
        floatx4 acc = {0.f, 0.f, 0.f, 0.f};
        const _Float16* brow = WT + (size_t)(nt*16 + r16)*K + quad*8;
        #pragma unroll
        for (int kt = 0; kt < KT; ++kt) {
            half8_t bfrag = *(const half8_t*)(brow + kt*32);
            acc = __builtin_amdgcn_mfma_f32_16x16x32_f16(afrag[kt], bfrag, acc, 0, 0, 0);
        }
        int col = nt*16 + r16;
        float bv = b2[col];
        if (nt < 8) {
            #pragma unroll
            for (int r = 0; r < 4; ++r)
                xl_h[(size_t)(m0 + quad*4 + r)*128 + col] = (_Float16)(acc[r] + bv);
        } else {
            #pragma unroll
            for (int r = 0; r < 4; ++r)
                xr[(size_t)(m0 + quad*4 + r)*128 + (col-128)] = acc[r] + bv;
        }
    }
}

// ---------------- GATv2 aggregation: one wave per node.
// New layout: 16 lanes per edge (8 ch/lane, one 16B half8 gather), 4 edge
// slots per wave. Max-free softmax (logits bounded; shift-invariant).
// leaky_relu(x) = 0.6x + 0.4|x|, |x| is a free VOP3 modifier.
__global__ __launch_bounds__(256) void k_gat(
    const _Float16* __restrict__ xl_h, const float* __restrict__ xr,
    const int* __restrict__ row_ptr, const int* __restrict__ csr_src,
    const float* __restrict__ att, const float* __restrict__ bias,
    float* __restrict__ hout, float2* __restrict__ nstats) {
    int wave = (blockIdx.x * 256 + threadIdx.x) >> 6;
    int lane = threadIdx.x & 63;
    if (wave >= N_NODES) return;
    int i = wave;
    int slot = lane >> 4;        // edge slot 0..3
    int l16  = lane & 15;        // lane within edge group
    int c0   = l16 * 8;          // 8 contiguous channels per lane (head = l16>>2)

    float attv[8], xrv[8];
    {
        const float4* a4 = (const float4*)(att + c0);
        const float4* r4 = (const float4*)(xr + (size_t)i*128 + c0);
        float4 a0 = a4[0], a1 = a4[1], r0 = r4[0], r1 = r4[1];
        attv[0]=a0.x; attv[1]=a0.y; attv[2]=a0.z; attv[3]=a0.w;
        attv[4]=a1.x; attv[5]=a1.y; attv[6]=a1.z; attv[7]=a1.w;
        xrv[0]=r0.x; xrv[1]=r0.y; xrv[2]=r0.z; xrv[3]=r0.w;
        xrv[4]=r1.x; xrv[5]=r1.y; xrv[6]=r1.z; xrv[7]=r1.w;
    }
    int p0 = row_ptr[i], p1 = row_ptr[i+1];

    float denom = 0.f;
    float acc[8];
    #pragma unroll
    for (int j = 0; j < 8; ++j) acc[j] = 0.f;

    for (int p = p0; p < p1; p += 8) {
        int e1 = p + slot, e2 = p + 4 + slot;
        int i1 = csr_src[(e1 < p1) ? e1 : (p1 - 1)];
        int i2 = csr_src[(e2 < p1) ? e2 : (p1 - 1)];
        half8_t g1 = *(const half8_t*)(xl_h + (size_t)i1*128 + c0);
        half8_t g2 = *(const half8_t*)(xl_h + (size_t)i2*128 + c0);
        float f1[8], f2[8];
        #pragma unroll
        for (int j = 0; j < 8; ++j) { f1[j] = (float)g1[j]; f2[j] = (float)g2[j]; }
        // logit partials: pt = 0.6*sum(m*att) + 0.4*sum(|m|*att)
        float pa1 = 0.f, pb1 = 0.f, pa2 = 0.f, pb2 = 0.f;
        #pragma unroll
        for (int j = 0; j < 8; ++j) {
            float m1 = f1[j] + xrv[j];
            float m2 = f2[j] + xrv[j];
            pa1 = fmaf(m1, attv[j], pa1);
            pb1 = fmaf(fabsf(m1), attv[j], pb1);
            pa2 = fmaf(m2, attv[j], pa2);
            pb2 = fmaf(fabsf(m2), attv[j], pb2);
        }
        float pt1 = 0.6f*pa1 + 0.4f*pb1;
        float pt2 = 0.6f*pa2 + 0.4f*pb2;
        // reduce across the 4 lanes of each head (bits 0,1 of lane)
        pt1 += __shfl_xor(pt1, 1);  pt2 += __shfl_xor(pt2, 1);
        pt1 += __shfl_xor(pt1, 2);  pt2 += __shfl_xor(pt2, 2);
        float w1 = (e1 < p1) ? __expf(pt1) : 0.f;
        float w2 = (e2 < p1) ? __expf(pt2) : 0.f;
        denom += w1 + w2;
        #pragma unroll
        for (int j = 0; j < 8; ++j) {
            acc[j] = fmaf(w1, f1[j], acc[j]);
            acc[j] = fmaf(w2, f2[j], acc[j]);
        }
    }
    // merge the 4 edge-slot chains (lanes differing in bits 4,5)
    #pragma unroll
    for (int off = 16; off <= 32; off <<= 1) {
        denom += __shfl_xor(denom, off);
        #pragma unroll
        for (int j = 0; j < 8; ++j) acc[j] += __shfl_xor(acc[j], off);
    }
    float inv = 1.f / (denom + 1e-16f);
    float v[8];
    float s1 = 0.f, s2 = 0.f;
    #pragma unroll
    for (int j = 0; j < 8; ++j) {
        v[j] = fmaf(acc[j], inv, 0.f) + bias[c0 + j];
        s1 += v[j];
        s2 = fmaf(v[j], v[j], s2);
    }
    if (slot == 0) {
        float4* o4 = (float4*)(hout + (size_t)i*128 + c0);
        o4[0] = make_float4(v[0], v[1], v[2], v[3]);
        o4[1] = make_float4(v[4], v[5], v[6], v[7]);
    }
    // LN stats: reduce across the 16 lanes of slot 0 (all slots identical)
    #pragma unroll
    for (int off = 1; off < 16; off <<= 1) {
        s1 += __shfl_xor(s1, off);
        s2 += __shfl_xor(s2, off);
    }
    if (lane == 0) nstats[i] = make_float2(s1, s2);
}

// ---------------- per-graph reduction of node stats (plain stores) ----------
__global__ __launch_bounds__(256) void k_graph_red(
    const float2* __restrict__ nstats, const int* __restrict__ goff,
    float* __restrict__ gsum, float* __restrict__ gsumsq) {
    __shared__ float l1[256], l2[256];
    int g = blockIdx.x;
    int tid = threadIdx.x;
    int a = goff[g], b = goff[g+1];
    float s1 = 0.f, s2 = 0.f;
    for (int i = a + tid; i < b; i += 256) {
        float2 v = nstats[i];
        s1 += v.x; s2 += v.y;
    }
    l1[tid] = s1; l2[tid] = s2; __syncthreads();
    for (int off = 128; off > 0; off >>= 1) {
        if (tid < off) { l1[tid] += l1[tid+off]; l2[tid] += l2[tid+off]; }
        __syncthreads();
    }
    if (tid == 0) { gsum[g] = l1[0]; gsumsq[g] = l2[0]; }
}

// ---------------- graph layernorm apply (fp16 out). For the last layer also
// writes hbw = h * link_W (w-folded copy used by k_pairs' fdot2 path). ----------
__global__ void k_ln(const float* __restrict__ hout, const int* __restrict__ batch,
                     const int* __restrict__ goff, const float* __restrict__ gsum,
                     const float* __restrict__ gsumsq, const float* __restrict__ w,
                     const float* __restrict__ b, _Float16* __restrict__ hb,
                     const float* __restrict__ linkW, _Float16* __restrict__ hbw) {
    int idx = blockIdx.x*256 + threadIdx.x;
    if (idx >= N_NODES*128) return;
    int i = idx >> 7, c = idx & 127;
    int g = batch[i];
    float cnt = (float)(goff[g+1] - goff[g]) * 128.f;
    cnt = fmaxf(cnt, 1.f);
    float mean = gsum[g] / cnt;
    float var = gsumsq[g] / cnt - mean*mean;
    var = fmaxf(var, 0.f);
    float rstd = rsqrtf(var + 1e-5f);
    float v = (hout[idx] - mean) * rstd * w[c] + b[c];
    hb[idx] = (_Float16)v;
    if (hbw) hbw[idx] = (_Float16)(v * linkW[c]);
}

// ---------------- pair scoring: 16 lanes/pair, fp16 half8 loads, fdot2 ------
__global__ __launch_bounds__(256) void k_pairs(
    const _Float16* __restrict__ hbw, const _Float16* __restrict__ hb,
    const int* __restrict__ pi, const float* __restrict__ lb,
    float* __restrict__ out) {
    int grp = (blockIdx.x*256 + threadIdx.x) >> 4;
    int q = threadIdx.x & 15;
    if (grp >= N_PAIRS) return;
    int p0 = pi[grp], p1 = pi[N_PAIRS + grp];
    const half8_t* A = (const half8_t*)hbw;
    const half8_t* B = (const half8_t*)hb;
    half8_t a = A[(size_t)p0*16 + q];
    half8_t b = B[(size_t)p1*16 + q];
    const half2_t* a2 = (const half2_t*)&a;
    const half2_t* b2 = (const half2_t*)&b;
    float part = 0.f;
    #pragma unroll
    for (int j = 0; j < 4; ++j)
        part = __builtin_amdgcn_fdot2(a2[j], b2[j], part, false);
    part += __shfl_xor(part, 1);
    part += __shfl_xor(part, 2);
    part += __shfl_xor(part, 4);
    part += __shfl_xor(part, 8);
    if (q == 0) out[grp] = 1.f / (1.f + __expf(-(part + lb[0])));
}

extern "C" void kernel_launch(void* const* d_in, const int* in_sizes, int n_in,
                              void* d_out, int out_size, void* d_ws, size_t ws_size,
                              hipStream_t stream) {
    const float* x     = (const float*)d_in[0];
    const float* t     = (const float*)d_in[1];
    const int*   ei    = (const int*)  d_in[2];
    const int*   pi    = (const int*)  d_in[3];
    const int*   batch = (const int*)  d_in[4];
    const float* tW    = (const float*)d_in[5];
    const float* tb    = (const float*)d_in[6];
    const float* W0l   = (const float*)d_in[7];
    const float* b0l   = (const float*)d_in[8];
    const float* W0r   = (const float*)d_in[9];
    const float* b0r   = (const float*)d_in[10];
    const float* att0  = (const float*)d_in[11];
    const float* bias0 = (const float*)d_in[12];
    const float* Wl    = (const float*)d_in[13];
    const float* bl    = (const float*)d_in[14];
    const float* Wr    = (const float*)d_in[15];
    const float* br    = (const float*)d_in[16];
    const float* att   = (const float*)d_in[17];
    const float* bias  = (const float*)d_in[18];
    const float* lnw   = (const float*)d_in[19];
    const float* lnb   = (const float*)d_in[20];
    const float* lW    = (const float*)d_in[21];
    const float* lb    = (const float*)d_in[22];
    float* out = (float*)d_out;

    char* ws = (char*)d_ws;
    size_t off = 0;
    auto walloc = [&](size_t bytes) -> void* {
        void* p = ws + off;
        off += (bytes + 255) & ~(size_t)255;
        return p;
    };
    _Float16*  h0h     = (_Float16*) walloc((size_t)N_NODES*384*2);
    float*     hout    = (float*)    walloc((size_t)N_NODES*128*4);
    _Float16*  xl_h    = (_Float16*) walloc((size_t)N_NODES*128*2);
    float*     xr      = (float*)    walloc((size_t)N_NODES*128*4);
    _Float16*  hb      = (_Float16*) walloc((size_t)N_NODES*128*2);
    _Float16*  hbw     = (_Float16*) walloc((size_t)N_NODES*128*2);
    int*       deg     = (int*)      walloc((size_t)N_NODES*4);   // reused as cursor
    int*       row_ptr = (int*)      walloc((size_t)(N_NODES+1)*4);
    int*       csr_src = (int*)      walloc((size_t)E_TOT*4);
    int*       bsums   = (int*)      walloc(256*4);
    int*       goff    = (int*)      walloc(64*4);
    float2*    nstats  = (float2*)   walloc((size_t)N_NODES*8);
    float*     stats   = (float*)    walloc(2*64*4);              // [sum|sumsq][64]
    _Float16*  WT0     = (_Float16*) walloc(256*384*2);
    _Float16*  WT123   = (_Float16*) walloc(3*256*128*2);
    float*     b2      = (float*)    walloc(4*256*4);

    hipMemsetAsync(deg, 0, (size_t)N_NODES*4, stream);

    k_time_embed<<<N_NODES, 256, 0, stream>>>(x, t, tW, tb, h0h);
    k_cvt_w<<<(256*384+255)/256, 256, 0, stream>>>(W0l, W0r, b0l, b0r, 384, WT0, b2);
    for (int l = 0; l < 3; ++l)
        k_cvt_w<<<(256*128+255)/256, 256, 0, stream>>>(
            Wl + (size_t)l*128*128, Wr + (size_t)l*128*128,
            bl + l*128, br + l*128, 128, WT123 + (size_t)l*256*128, b2 + (l+1)*256);
    k_edge_hist<<<(E_TOT+255)/256, 256, 0, stream>>>(ei, deg);
    k_goff<<<SCAN_NB, 256, 0, stream>>>(batch, goff);
    k_scan1<<<SCAN_NB, 256, 0, stream>>>(deg, row_ptr, bsums);
    k_scan2<<<1, 256, 0, stream>>>(bsums, SCAN_NB);
    k_scan3<<<SCAN_NB, 256, 0, stream>>>(row_ptr, bsums, deg);   // deg becomes cursor
    k_scatter<<<(E_TOT+255)/256, 256, 0, stream>>>(ei, deg, csr_src);

    float* gsum   = stats;
    float* gsumsq = stats + 64;
    const int GEMM_BLOCKS = (N_NODES/16 + 3) / 4;   // 4 waves/block, 16 rows/wave
    for (int L = 0; L < 4; ++L) {
        if (L == 0)
            k_gemm_mfma<384><<<GEMM_BLOCKS, 256, 0, stream>>>(h0h, WT0, b2, xl_h, xr);
        else
            k_gemm_mfma<128><<<GEMM_BLOCKS, 256, 0, stream>>>(
                hb, WT123 + (size_t)(L-1)*256*128, b2 + L*256, xl_h, xr);
        const float* attL  = (L == 0) ? att0  : att  + (size_t)(L-1)*128;
        const float* biasL = (L == 0) ? bias0 : bias + (size_t)(L-1)*128;
        k_gat<<<N_NODES/4, 256, 0, stream>>>(xl_h, xr, row_ptr, csr_src, attL, biasL,
                                             hout, nstats);
        k_graph_red<<<N_GRAPHS, 256, 0, stream>>>(nstats, goff, gsum, gsumsq);
        k_ln<<<(N_NODES*128+255)/256, 256, 0, stream>>>(
            hout, batch, goff, gsum, gsumsq, lnw + L*128, lnb + L*128, hb,
            lW, (L == 3) ? hbw : (_Float16*)nullptr);
    }

    k_pairs<<<((size_t)N_PAIRS*16 + 255)/256, 256, 0, stream>>>(hbw, hb, pi, lb, out);
}

// Round 8
// 958.971 us; speedup vs baseline: 3.7206x; 1.1083x over previous
//
#include <hip/hip_runtime.h>
#include <hip/hip_bf16.h>
#include <hip/hip_fp16.h>

#define N_NODES 50000
#define N_EDGES 1600000
#define E_TOT   1650000   // N_EDGES + N_NODES self loops
#define N_PAIRS 2000000
#define N_GRAPHS 50
#define SCAN_NB 196       // ceil(N_NODES/256)

typedef __attribute__((ext_vector_type(2))) _Float16 half2_t;
typedef __attribute__((ext_vector_type(4))) _Float16 half4_t;
typedef __attribute__((ext_vector_type(8))) _Float16 half8_t;
typedef __attribute__((ext_vector_type(4))) float floatx4;

union H8 { half8_t v; half2_t h2[4]; uint32_t u[4]; };

// ---------------- time embedding: h0h[:, :128]=x, h0h[:,128:384]=swish(...) (fp16 out)
__global__ void k_time_embed(const float* __restrict__ x, const float* __restrict__ t,
                             const float* __restrict__ tW, const float* __restrict__ tb,
                             _Float16* __restrict__ h0h) {
    int i = blockIdx.x;
    int tid = threadIdx.x;
    float ta = t[i];                       // T_LIMIT = 1.0
    float s = sinf(ta * 1.5707963267948966f);
    float c = cosf(ta * 1.5707963267948966f);
    if (tid < 128) h0h[(size_t)i*384 + tid] = (_Float16)x[(size_t)i*128 + tid];
    float v = s*tW[tid] + c*tW[256+tid] + ta*tW[512+tid] + tb[tid];
    float sw = v / (1.f + __expf(-v));
    h0h[(size_t)i*384 + 128 + tid] = (_Float16)sw;
}

// ---------------- weight convert: WT[n][k] = (n<128?Wl:Wr)[k][n&127] as fp16; b2 combined
__global__ void k_cvt_w(const float* __restrict__ Wl, const float* __restrict__ Wr,
                        const float* __restrict__ bl, const float* __restrict__ br,
                        int K, _Float16* __restrict__ WT, float* __restrict__ b2) {
    int idx = blockIdx.x*256 + threadIdx.x;
    if (idx < 256) b2[idx] = (idx < 128) ? bl[idx] : br[idx-128];
    if (idx >= 256*K) return;
    int n = idx / K, k = idx - n*K;
    float v = (n < 128) ? Wl[k*128 + n] : Wr[k*128 + (n-128)];
    WT[idx] = (_Float16)v;
}

// ---------------- CSR build ----------------
__global__ void k_edge_hist(const int* __restrict__ ei, int* __restrict__ deg) {
    int e = blockIdx.x*256 + threadIdx.x;
    if (e >= E_TOT) return;
    int dst = (e < N_EDGES) ? ei[N_EDGES + e] : (e - N_EDGES);
    atomicAdd(&deg[dst], 1);
}

// batch is sorted: derive graph offsets without atomics
__global__ void k_goff(const int* __restrict__ batch, int* __restrict__ goff) {
    int i = blockIdx.x*256 + threadIdx.x;
    if (i >= N_NODES) return;
    int bi = batch[i];
    if (i == 0) {
        for (int g = 0; g <= bi; ++g) goff[g] = 0;
    } else {
        int bp = batch[i-1];
        for (int g = bp+1; g <= bi; ++g) goff[g] = i;
    }
    if (i == N_NODES-1) {
        for (int g = bi+1; g <= N_GRAPHS; ++g) goff[g] = N_NODES;
    }
}

__global__ void k_scan1(const int* __restrict__ deg, int* __restrict__ row_ptr,
                        int* __restrict__ bsums) {
    __shared__ int tmp[256];
    int tid = threadIdx.x;
    int i = blockIdx.x*256 + tid;
    int v = (i < N_NODES) ? deg[i] : 0;
    tmp[tid] = v; __syncthreads();
    for (int off = 1; off < 256; off <<= 1) {
        int tv = (tid >= off) ? tmp[tid-off] : 0;
        __syncthreads();
        tmp[tid] += tv;
        __syncthreads();
    }
    int inc = tmp[tid];
    if (i < N_NODES) row_ptr[i] = inc - v;     // block-local exclusive
    if (tid == 255) bsums[blockIdx.x] = inc;
}

__global__ void k_scan2(int* __restrict__ bsums, int nb) {
    __shared__ int tmp[256];
    int tid = threadIdx.x;
    int v = (tid < nb) ? bsums[tid] : 0;
    tmp[tid] = v; __syncthreads();
    for (int off = 1; off < 256; off <<= 1) {
        int tv = (tid >= off) ? tmp[tid-off] : 0;
        __syncthreads();
        tmp[tid] += tv;
        __syncthreads();
    }
    bsums[tid] = tmp[tid] - v;                 // exclusive over block sums
}

__global__ void k_scan3(int* __restrict__ row_ptr, const int* __restrict__ bsums,
                        int* __restrict__ cursor) {
    int i = blockIdx.x*256 + threadIdx.x;
    if (i < N_NODES) {
        int v = row_ptr[i] + bsums[blockIdx.x];
        row_ptr[i] = v;
        cursor[i] = v;
    }
    if (i == 0) row_ptr[N_NODES] = E_TOT;
}

__global__ void k_scatter(const int* __restrict__ ei, int* __restrict__ cursor,
                          int* __restrict__ csr_src) {
    int e = blockIdx.x*256 + threadIdx.x;
    if (e >= E_TOT) return;
    int src, dst;
    if (e < N_EDGES) { src = ei[e]; dst = ei[N_EDGES + e]; }
    else             { src = e - N_EDGES; dst = src; }
    int pos = atomicAdd(&cursor[dst], 1);
    csr_src[pos] = src;
}

// ---------------- dual GEMM via MFMA (fp16 A input, layer 0) ----------------
template<int K>
__global__ __launch_bounds__(256) void k_gemm_mfma(
    const _Float16* __restrict__ Ah, const _Float16* __restrict__ WT,
    const float* __restrict__ b2,
    _Float16* __restrict__ xl_h, float* __restrict__ xr) {
    int wave = (blockIdx.x*256 + threadIdx.x) >> 6;
    int lane = threadIdx.x & 63;
    if (wave >= N_NODES/16) return;
    int m0 = wave * 16;
    int r16 = lane & 15, quad = lane >> 4;
    constexpr int KT = K / 32;
    half8_t afrag[KT];
    const _Float16* arow = Ah + (size_t)(m0 + r16)*K + quad*8;
    #pragma unroll
    for (int kt = 0; kt < KT; ++kt)
        afrag[kt] = *(const half8_t*)(arow + kt*32);
    #pragma unroll
    for (int nt = 0; nt < 16; ++nt) {
        floatx4 acc = {0.f, 0.f, 0.f, 0.f};
        const _Float16* brow = WT + (size_t)(nt*16 + r16)*K + quad*8;
        #pragma unroll
        for (int kt = 0; kt < KT; ++kt) {
            half8_t bfrag = *(const half8_t*)(brow + kt*32);
            acc = __builtin_amdgcn_mfma_f32_16x16x32_f16(afrag[kt], bfrag, acc, 0, 0, 0);
        }
        int col = nt*16 + r16;
        float bv = b2[col];
        if (nt < 8) {
            #pragma unroll
            for (int r = 0; r < 4; ++r)
                xl_h[(size_t)(m0 + quad*4 + r)*128 + col] = (_Float16)(acc[r] + bv);
        } else {
            #pragma unroll
            for (int r = 0; r < 4; ++r)
                xr[(size_t)(m0 + quad*4 + r)*128 + (col-128)] = acc[r] + bv;
        }
    }
}

// ---------------- dual GEMM via MFMA with FUSED graph-LN on the input
// (layers 1..3): A = LN(hout) applied while packing fragments. K=128.
__global__ __launch_bounds__(256) void k_gemm_ln_mfma(
    const float* __restrict__ hout, const int* __restrict__ batch,
    const int* __restrict__ goff, const float* __restrict__ gsum,
    const float* __restrict__ gsumsq, const float* __restrict__ lnw,
    const float* __restrict__ lnb, const _Float16* __restrict__ WT,
    const float* __restrict__ b2,
    _Float16* __restrict__ xl_h, float* __restrict__ xr) {
    int wave = (blockIdx.x*256 + threadIdx.x) >> 6;
    int lane = threadIdx.x & 63;
    if (wave >= N_NODES/16) return;
    int m0 = wave * 16;
    int r16 = lane & 15, quad = lane >> 4;
    int row = m0 + r16;
    int g = batch[row];
    float cnt = (float)(goff[g+1] - goff[g]) * 128.f;
    cnt = fmaxf(cnt, 1.f);
    float mean = gsum[g] / cnt;
    float var = gsumsq[g] / cnt - mean*mean;
    var = fmaxf(var, 0.f);
    float rstd = rsqrtf(var + 1e-5f);

    half8_t afrag[4];
    const float* arow = hout + (size_t)row*128 + quad*8;
    #pragma unroll
    for (int kt = 0; kt < 4; ++kt) {
        int c = quad*8 + kt*32;
        const float4* v4 = (const float4*)(arow + kt*32);
        const float4* w4 = (const float4*)(lnw + c);
        const float4* b4 = (const float4*)(lnb + c);
        float4 v0 = v4[0], v1 = v4[1];
        float4 w0 = w4[0], w1 = w4[1];
        float4 bb0 = b4[0], bb1 = b4[1];
        float vv[8] = {v0.x,v0.y,v0.z,v0.w,v1.x,v1.y,v1.z,v1.w};
        float ww[8] = {w0.x,w0.y,w0.z,w0.w,w1.x,w1.y,w1.z,w1.w};
        float bz[8] = {bb0.x,bb0.y,bb0.z,bb0.w,bb1.x,bb1.y,bb1.z,bb1.w};
        #pragma unroll
        for (int j = 0; j < 8; ++j)
            afrag[kt][j] = (_Float16)((vv[j] - mean) * rstd * ww[j] + bz[j]);
    }
    #pragma unroll
    for (int nt = 0; nt < 16; ++nt) {
        floatx4 acc = {0.f, 0.f, 0.f, 0.f};
        const _Float16* brow = WT + (size_t)(nt*16 + r16)*128 + quad*8;
        #pragma unroll
        for (int kt = 0; kt < 4; ++kt) {
            half8_t bfrag = *(const half8_t*)(brow + kt*32);
            acc = __builtin_amdgcn_mfma_f32_16x16x32_f16(afrag[kt], bfrag, acc, 0, 0, 0);
        }
        int col = nt*16 + r16;
        float bv = b2[col];
        if (nt < 8) {
            #pragma unroll
            for (int r = 0; r < 4; ++r)
                xl_h[(size_t)(m0 + quad*4 + r)*128 + col] = (_Float16)(acc[r] + bv);
        } else {
            #pragma unroll
            for (int r = 0; r < 4; ++r)
                xr[(size_t)(m0 + quad*4 + r)*128 + (col-128)] = acc[r] + bv;
        }
    }
}

// ---------------- GATv2 aggregation: one wave per node.
// 16 lanes per edge (8 ch/lane, one 16B half8 gather), 4 edge slots/wave.
// Max-free softmax. Logit math in packed fp16: m via v_pk_add_f16, |m| via
// one v_and_b32, dot via v_dot2_f32_f16 (f32 accumulate).
__global__ __launch_bounds__(256) void k_gat(
    const _Float16* __restrict__ xl_h, const float* __restrict__ xr,
    const int* __restrict__ row_ptr, const int* __restrict__ csr_src,
    const float* __restrict__ att, const float* __restrict__ bias,
    float* __restrict__ hout, float2* __restrict__ nstats) {
    int wave = (blockIdx.x * 256 + threadIdx.x) >> 6;
    int lane = threadIdx.x & 63;
    if (wave >= N_NODES) return;
    int i = wave;
    int slot = lane >> 4;        // edge slot 0..3
    int l16  = lane & 15;        // lane within edge group
    int c0   = l16 * 8;          // 8 contiguous channels per lane

    H8 atth, xrh;
    {
        const float4* a4 = (const float4*)(att + c0);
        const float4* r4 = (const float4*)(xr + (size_t)i*128 + c0);
        float4 a0 = a4[0], a1 = a4[1], r0 = r4[0], r1 = r4[1];
        float af[8] = {a0.x,a0.y,a0.z,a0.w,a1.x,a1.y,a1.z,a1.w};
        float rf[8] = {r0.x,r0.y,r0.z,r0.w,r1.x,r1.y,r1.z,r1.w};
        #pragma unroll
        for (int j = 0; j < 8; ++j) {
            atth.v[j] = (_Float16)af[j];
            xrh.v[j]  = (_Float16)rf[j];
        }
    }
    int p0 = row_ptr[i], p1 = row_ptr[i+1];

    float denom = 0.f;
    float acc[8];
    #pragma unroll
    for (int j = 0; j < 8; ++j) acc[j] = 0.f;

    for (int p = p0; p < p1; p += 8) {
        int e1 = p + slot, e2 = p + 4 + slot;
        int i1 = csr_src[(e1 < p1) ? e1 : (p1 - 1)];
        int i2 = csr_src[(e2 < p1) ? e2 : (p1 - 1)];
        H8 g1, g2, m1, m2;
        g1.v = *(const half8_t*)(xl_h + (size_t)i1*128 + c0);
        g2.v = *(const half8_t*)(xl_h + (size_t)i2*128 + c0);
        m1.v = g1.v + xrh.v;
        m2.v = g2.v + xrh.v;
        float pa1 = 0.f, pb1 = 0.f, pa2 = 0.f, pb2 = 0.f;
        #pragma unroll
        for (int j = 0; j < 4; ++j) {
            half2_t ab1 = __builtin_bit_cast(half2_t, m1.u[j] & 0x7FFF7FFFu);
            half2_t ab2 = __builtin_bit_cast(half2_t, m2.u[j] & 0x7FFF7FFFu);
            pa1 = __builtin_amdgcn_fdot2(m1.h2[j], atth.h2[j], pa1, false);
            pb1 = __builtin_amdgcn_fdot2(ab1,      atth.h2[j], pb1, false);
            pa2 = __builtin_amdgcn_fdot2(m2.h2[j], atth.h2[j], pa2, false);
            pb2 = __builtin_amdgcn_fdot2(ab2,      atth.h2[j], pb2, false);
        }
        float pt1 = 0.6f*pa1 + 0.4f*pb1;
        float pt2 = 0.6f*pa2 + 0.4f*pb2;
        pt1 += __shfl_xor(pt1, 1);  pt2 += __shfl_xor(pt2, 1);
        pt1 += __shfl_xor(pt1, 2);  pt2 += __shfl_xor(pt2, 2);
        float w1 = (e1 < p1) ? __expf(pt1) : 0.f;
        float w2 = (e2 < p1) ? __expf(pt2) : 0.f;
        denom += w1 + w2;
        #pragma unroll
        for (int j = 0; j < 8; ++j) {
            acc[j] = fmaf(w1, (float)g1.v[j], acc[j]);
            acc[j] = fmaf(w2, (float)g2.v[j], acc[j]);
        }
    }
    // merge the 4 edge-slot chains (lanes differing in bits 4,5)
    #pragma unroll
    for (int off = 16; off <= 32; off <<= 1) {
        denom += __shfl_xor(denom, off);
        #pragma unroll
        for (int j = 0; j < 8; ++j) acc[j] += __shfl_xor(acc[j], off);
    }
    float inv = 1.f / (denom + 1e-16f);
    float v[8];
    float s1 = 0.f, s2 = 0.f;
    #pragma unroll
    for (int j = 0; j < 8; ++j) {
        v[j] = acc[j] * inv + bias[c0 + j];
        s1 += v[j];
        s2 = fmaf(v[j], v[j], s2);
    }
    if (slot == 0) {
        float4* o4 = (float4*)(hout + (size_t)i*128 + c0);
        o4[0] = make_float4(v[0], v[1], v[2], v[3]);
        o4[1] = make_float4(v[4], v[5], v[6], v[7]);
    }
    #pragma unroll
    for (int off = 1; off < 16; off <<= 1) {
        s1 += __shfl_xor(s1, off);
        s2 += __shfl_xor(s2, off);
    }
    if (lane == 0) nstats[i] = make_float2(s1, s2);
}

// ---------------- per-graph reduction of node stats (plain stores) ----------
__global__ __launch_bounds__(256) void k_graph_red(
    const float2* __restrict__ nstats, const int* __restrict__ goff,
    float* __restrict__ gsum, float* __restrict__ gsumsq) {
    __shared__ float l1[256], l2[256];
    int g = blockIdx.x;
    int tid = threadIdx.x;
    int a = goff[g], b = goff[g+1];
    float s1 = 0.f, s2 = 0.f;
    for (int i = a + tid; i < b; i += 256) {
        float2 v = nstats[i];
        s1 += v.x; s2 += v.y;
    }
    l1[tid] = s1; l2[tid] = s2; __syncthreads();
    for (int off = 128; off > 0; off >>= 1) {
        if (tid < off) { l1[tid] += l1[tid+off]; l2[tid] += l2[tid+off]; }
        __syncthreads();
    }
    if (tid == 0) { gsum[g] = l1[0]; gsumsq[g] = l2[0]; }
}

// ---------------- final graph layernorm (fp16 out, feeds k_pairs only) -------
__global__ void k_ln(const float* __restrict__ hout, const int* __restrict__ batch,
                     const int* __restrict__ goff, const float* __restrict__ gsum,
                     const float* __restrict__ gsumsq, const float* __restrict__ w,
                     const float* __restrict__ b, _Float16* __restrict__ hb) {
    int idx = blockIdx.x*256 + threadIdx.x;
    if (idx >= N_NODES*128) return;
    int i = idx >> 7, c = idx & 127;
    int g = batch[i];
    float cnt = (float)(goff[g+1] - goff[g]) * 128.f;
    cnt = fmaxf(cnt, 1.f);
    float mean = gsum[g] / cnt;
    float var = gsumsq[g] / cnt - mean*mean;
    var = fmaxf(var, 0.f);
    float rstd = rsqrtf(var + 1e-5f);
    float v = (hout[idx] - mean) * rstd * w[c] + b[c];
    hb[idx] = (_Float16)v;
}

// ---------------- pair scoring: 16 lanes/pair, SINGLE gathered array,
// link_W folded into per-lane fp16 registers ----------
__global__ __launch_bounds__(256) void k_pairs(
    const _Float16* __restrict__ hb, const int* __restrict__ pi,
    const float* __restrict__ lW, const float* __restrict__ lb,
    float* __restrict__ out) {
    int grp = (blockIdx.x*256 + threadIdx.x) >> 4;
    int q = threadIdx.x & 15;
    if (grp >= N_PAIRS) return;
    H8 w;
    #pragma unroll
    for (int j = 0; j < 8; ++j) w.v[j] = (_Float16)lW[q*8 + j];
    int p0 = pi[grp], p1 = pi[N_PAIRS + grp];
    const half8_t* B = (const half8_t*)hb;
    H8 a, b, prod;
    a.v = B[(size_t)p0*16 + q];
    b.v = B[(size_t)p1*16 + q];
    prod.v = a.v * b.v;
    float part = 0.f;
    #pragma unroll
    for (int j = 0; j < 4; ++j)
        part = __builtin_amdgcn_fdot2(prod.h2[j], w.h2[j], part, false);
    part += __shfl_xor(part, 1);
    part += __shfl_xor(part, 2);
    part += __shfl_xor(part, 4);
    part += __shfl_xor(part, 8);
    if (q == 0) out[grp] = 1.f / (1.f + __expf(-(part + lb[0])));
}

extern "C" void kernel_launch(void* const* d_in, const int* in_sizes, int n_in,
                              void* d_out, int out_size, void* d_ws, size_t ws_size,
                              hipStream_t stream) {
    const float* x     = (const float*)d_in[0];
    const float* t     = (const float*)d_in[1];
    const int*   ei    = (const int*)  d_in[2];
    const int*   pi    = (const int*)  d_in[3];
    const int*   batch = (const int*)  d_in[4];
    const float* tW    = (const float*)d_in[5];
    const float* tb    = (const float*)d_in[6];
    const float* W0l   = (const float*)d_in[7];
    const float* b0l   = (const float*)d_in[8];
    const float* W0r   = (const float*)d_in[9];
    const float* b0r   = (const float*)d_in[10];
    const float* att0  = (const float*)d_in[11];
    const float* bias0 = (const float*)d_in[12];
    const float* Wl    = (const float*)d_in[13];
    const float* bl    = (const float*)d_in[14];
    const float* Wr    = (const float*)d_in[15];
    const float* br    = (const float*)d_in[16];
    const float* att   = (const float*)d_in[17];
    const float* bias  = (const float*)d_in[18];
    const float* lnw   = (const float*)d_in[19];
    const float* lnb   = (const float*)d_in[20];
    const float* lW    = (const float*)d_in[21];
    const float* lb    = (const float*)d_in[22];
    float* out = (float*)d_out;

    char* ws = (char*)d_ws;
    size_t off = 0;
    auto walloc = [&](size_t bytes) -> void* {
        void* p = ws + off;
        off += (bytes + 255) & ~(size_t)255;
        return p;
    };
    _Float16*  h0h     = (_Float16*) walloc((size_t)N_NODES*384*2);
    float*     hout    = (float*)    walloc((size_t)N_NODES*128*4);
    _Float16*  xl_h    = (_Float16*) walloc((size_t)N_NODES*128*2);
    float*     xr      = (float*)    walloc((size_t)N_NODES*128*4);
    _Float16*  hb      = (_Float16*) walloc((size_t)N_NODES*128*2);
    int*       deg     = (int*)      walloc((size_t)N_NODES*4);   // reused as cursor
    int*       row_ptr = (int*)      walloc((size_t)(N_NODES+1)*4);
    int*       csr_src = (int*)      walloc((size_t)E_TOT*4);
    int*       bsums   = (int*)      walloc(256*4);
    int*       goff    = (int*)      walloc(64*4);
    float2*    nstats  = (float2*)   walloc((size_t)N_NODES*8);
    float*     stats   = (float*)    walloc(2*64*4);              // [sum|sumsq][64]
    _Float16*  WT0     = (_Float16*) walloc(256*384*2);
    _Float16*  WT123   = (_Float16*) walloc(3*256*128*2);
    float*     b2      = (float*)    walloc(4*256*4);

    hipMemsetAsync(deg, 0, (size_t)N_NODES*4, stream);

    k_time_embed<<<N_NODES, 256, 0, stream>>>(x, t, tW, tb, h0h);
    k_cvt_w<<<(256*384+255)/256, 256, 0, stream>>>(W0l, W0r, b0l, b0r, 384, WT0, b2);
    for (int l = 0; l < 3; ++l)
        k_cvt_w<<<(256*128+255)/256, 256, 0, stream>>>(
            Wl + (size_t)l*128*128, Wr + (size_t)l*128*128,
            bl + l*128, br + l*128, 128, WT123 + (size_t)l*256*128, b2 + (l+1)*256);
    k_edge_hist<<<(E_TOT+255)/256, 256, 0, stream>>>(ei, deg);
    k_goff<<<SCAN_NB, 256, 0, stream>>>(batch, goff);
    k_scan1<<<SCAN_NB, 256, 0, stream>>>(deg, row_ptr, bsums);
    k_scan2<<<1, 256, 0, stream>>>(bsums, SCAN_NB);
    k_scan3<<<SCAN_NB, 256, 0, stream>>>(row_ptr, bsums, deg);   // deg becomes cursor
    k_scatter<<<(E_TOT+255)/256, 256, 0, stream>>>(ei, deg, csr_src);

    float* gsum   = stats;
    float* gsumsq = stats + 64;
    const int GEMM_BLOCKS = (N_NODES/16 + 3) / 4;   // 4 waves/block, 16 rows/wave
    for (int L = 0; L < 4; ++L) {
        if (L == 0)
            k_gemm_mfma<384><<<GEMM_BLOCKS, 256, 0, stream>>>(h0h, WT0, b2, xl_h, xr);
        else
            k_gemm_ln_mfma<<<GEMM_BLOCKS, 256, 0, stream>>>(
                hout, batch, goff, gsum, gsumsq, lnw + (L-1)*128, lnb + (L-1)*128,
                WT123 + (size_t)(L-1)*256*128, b2 + L*256, xl_h, xr);
        const float* attL  = (L == 0) ? att0  : att  + (size_t)(L-1)*128;
        const float* biasL = (L == 0) ? bias0 : bias + (size_t)(L-1)*128;
        k_gat<<<N_NODES/4, 256, 0, stream>>>(xl_h, xr, row_ptr, csr_src, attL, biasL,
                                             hout, nstats);
        k_graph_red<<<N_GRAPHS, 256, 0, stream>>>(nstats, goff, gsum, gsumsq);
    }
    k_ln<<<(N_NODES*128+255)/256, 256, 0, stream>>>(hout, batch, goff, gsum, gsumsq,
                                                    lnw + 3*128, lnb + 3*128, hb);
    k_pairs<<<((size_t)N_PAIRS*16 + 255)/256, 256, 0, stream>>>(hb, pi, lW, lb, out);
}

// Round 9
// 955.767 us; speedup vs baseline: 3.7331x; 1.0034x over previous
//
#include <hip/hip_runtime.h>
#include <hip/hip_bf16.h>
#include <hip/hip_fp16.h>

#define N_NODES 50000
#define N_EDGES 1600000
#define E_TOT   1650000   // N_EDGES + N_NODES self loops
#define N_PAIRS 2000000
#define N_GRAPHS 50
#define SCAN_NB 196       // ceil(N_NODES/256)
#define CPAD 16           // cursor padding: one int per 64B line

typedef __attribute__((ext_vector_type(2))) _Float16 half2_t;
typedef __attribute__((ext_vector_type(4))) _Float16 half4_t;
typedef __attribute__((ext_vector_type(8))) _Float16 half8_t;
typedef __attribute__((ext_vector_type(4))) float floatx4;

union H8 { half8_t v; half2_t h2[4]; uint32_t u[4]; };

// ---------------- time embedding: h0h[:, :128]=x, h0h[:,128:384]=swish(...) (fp16 out)
__global__ void k_time_embed(const float* __restrict__ x, const float* __restrict__ t,
                             const float* __restrict__ tW, const float* __restrict__ tb,
                             _Float16* __restrict__ h0h) {
    int i = blockIdx.x;
    int tid = threadIdx.x;
    float ta = t[i];                       // T_LIMIT = 1.0
    float s = sinf(ta * 1.5707963267948966f);
    float c = cosf(ta * 1.5707963267948966f);
    if (tid < 128) h0h[(size_t)i*384 + tid] = (_Float16)x[(size_t)i*128 + tid];
    float v = s*tW[tid] + c*tW[256+tid] + ta*tW[512+tid] + tb[tid];
    float sw = v / (1.f + __expf(-v));
    h0h[(size_t)i*384 + 128 + tid] = (_Float16)sw;
}

// ---------------- weight convert: WT[n][k] = (n<128?Wl:Wr)[k][n&127] as fp16; b2 combined
__global__ void k_cvt_w(const float* __restrict__ Wl, const float* __restrict__ Wr,
                        const float* __restrict__ bl, const float* __restrict__ br,
                        int K, _Float16* __restrict__ WT, float* __restrict__ b2) {
    int idx = blockIdx.x*256 + threadIdx.x;
    if (idx < 256) b2[idx] = (idx < 128) ? bl[idx] : br[idx-128];
    if (idx >= 256*K) return;
    int n = idx / K, k = idx - n*K;
    float v = (n < 128) ? Wl[k*128 + n] : Wr[k*128 + (n-128)];
    WT[idx] = (_Float16)v;
}

// ---------------- CSR build (padded counters: 1 int per 64B line) ----------
__global__ void k_edge_hist(const int* __restrict__ ei, int* __restrict__ degp) {
    int e = blockIdx.x*256 + threadIdx.x;
    if (e >= E_TOT) return;
    int dst = (e < N_EDGES) ? ei[N_EDGES + e] : (e - N_EDGES);
    atomicAdd(&degp[(size_t)dst*CPAD], 1);
}

// batch is sorted: derive graph offsets without atomics
__global__ void k_goff(const int* __restrict__ batch, int* __restrict__ goff) {
    int i = blockIdx.x*256 + threadIdx.x;
    if (i >= N_NODES) return;
    int bi = batch[i];
    if (i == 0) {
        for (int g = 0; g <= bi; ++g) goff[g] = 0;
    } else {
        int bp = batch[i-1];
        for (int g = bp+1; g <= bi; ++g) goff[g] = i;
    }
    if (i == N_NODES-1) {
        for (int g = bi+1; g <= N_GRAPHS; ++g) goff[g] = N_NODES;
    }
}

__global__ void k_scan1(const int* __restrict__ degp, int* __restrict__ row_ptr,
                        int* __restrict__ bsums) {
    __shared__ int tmp[256];
    int tid = threadIdx.x;
    int i = blockIdx.x*256 + tid;
    int v = (i < N_NODES) ? degp[(size_t)i*CPAD] : 0;
    tmp[tid] = v; __syncthreads();
    for (int off = 1; off < 256; off <<= 1) {
        int tv = (tid >= off) ? tmp[tid-off] : 0;
        __syncthreads();
        tmp[tid] += tv;
        __syncthreads();
    }
    int inc = tmp[tid];
    if (i < N_NODES) row_ptr[i] = inc - v;     // block-local exclusive
    if (tid == 255) bsums[blockIdx.x] = inc;
}

__global__ void k_scan2(int* __restrict__ bsums, int nb) {
    __shared__ int tmp[256];
    int tid = threadIdx.x;
    int v = (tid < nb) ? bsums[tid] : 0;
    tmp[tid] = v; __syncthreads();
    for (int off = 1; off < 256; off <<= 1) {
        int tv = (tid >= off) ? tmp[tid-off] : 0;
        __syncthreads();
        tmp[tid] += tv;
        __syncthreads();
    }
    bsums[tid] = tmp[tid] - v;                 // exclusive over block sums
}

__global__ void k_scan3(int* __restrict__ row_ptr, const int* __restrict__ bsums,
                        int* __restrict__ cursorp) {
    int i = blockIdx.x*256 + threadIdx.x;
    if (i < N_NODES) {
        int v = row_ptr[i] + bsums[blockIdx.x];
        row_ptr[i] = v;
        cursorp[(size_t)i*CPAD] = v;
    }
    if (i == 0) row_ptr[N_NODES] = E_TOT;
}

// 4 independent edges per thread (block-strided, coalesced) -> 4 parallel
// atomic-return chains; padded cursors kill same-line RMW serialization.
__global__ __launch_bounds__(256) void k_scatter(
    const int* __restrict__ ei, int* __restrict__ cursorp,
    int* __restrict__ csr_src) {
    int base = blockIdx.x*1024 + threadIdx.x;
    #pragma unroll
    for (int j = 0; j < 4; ++j) {
        int e = base + j*256;
        if (e >= E_TOT) continue;
        int src, dst;
        if (e < N_EDGES) { src = ei[e]; dst = ei[N_EDGES + e]; }
        else             { src = e - N_EDGES; dst = src; }
        int pos = atomicAdd(&cursorp[(size_t)dst*CPAD], 1);
        csr_src[pos] = src;
    }
}

// ---------------- dual GEMM via MFMA (fp16 A input, layer 0) ----------------
template<int K>
__global__ __launch_bounds__(256) void k_gemm_mfma(
    const _Float16* __restrict__ Ah, const _Float16* __restrict__ WT,
    const float* __restrict__ b2,
    _Float16* __restrict__ xl_h, float* __restrict__ xr) {
    int wave = (blockIdx.x*256 + threadIdx.x) >> 6;
    int lane = threadIdx.x & 63;
    if (wave >= N_NODES/16) return;
    int m0 = wave * 16;
    int r16 = lane & 15, quad = lane >> 4;
    constexpr int KT = K / 32;
    half8_t afrag[KT];
    const _Float16* arow = Ah + (size_t)(m0 + r16)*K + quad*8;
    #pragma unroll
    for (int kt = 0; kt < KT; ++kt)
        afrag[kt] = *(const half8_t*)(arow + kt*32);
    #pragma unroll
    for (int nt = 0; nt < 16; ++nt) {
        floatx4 acc = {0.f, 0.f, 0.f, 0.f};
        const _Float16* brow = WT + (size_t)(nt*16 + r16)*K + quad*8;
        #pragma unroll
        for (int kt = 0; kt < KT; ++kt) {
            half8_t bfrag = *(const half8_t*)(brow + kt*32);
            acc = __builtin_amdgcn_mfma_f32_16x16x32_f16(afrag[kt], bfrag, acc, 0, 0, 0);
        }
        int col = nt*16 + r16;
        float bv = b2[col];
        if (nt < 8) {
            #pragma unroll
            for (int r = 0; r < 4; ++r)
                xl_h[(size_t)(m0 + quad*4 + r)*128 + col] = (_Float16)(acc[r] + bv);
        } else {
            #pragma unroll
            for (int r = 0; r < 4; ++r)
                xr[(size_t)(m0 + quad*4 + r)*128 + (col-128)] = acc[r] + bv;
        }
    }
}

// ---------------- dual GEMM via MFMA with FUSED graph-LN on the input
// (layers 1..3): A = LN(hout) applied while packing fragments. K=128.
__global__ __launch_bounds__(256) void k_gemm_ln_mfma(
    const float* __restrict__ hout, const int* __restrict__ batch,
    const int* __restrict__ goff, const float* __restrict__ gsum,
    const float* __restrict__ gsumsq, const float* __restrict__ lnw,
    const float* __restrict__ lnb, const _Float16* __restrict__ WT,
    const float* __restrict__ b2,
    _Float16* __restrict__ xl_h, float* __restrict__ xr) {
    int wave = (blockIdx.x*256 + threadIdx.x) >> 6;
    int lane = threadIdx.x & 63;
    if (wave >= N_NODES/16) return;
    int m0 = wave * 16;
    int r16 = lane & 15, quad = lane >> 4;
    int row = m0 + r16;
    int g = batch[row];
    float cnt = (float)(goff[g+1] - goff[g]) * 128.f;
    cnt = fmaxf(cnt, 1.f);
    float mean = gsum[g] / cnt;
    float var = gsumsq[g] / cnt - mean*mean;
    var = fmaxf(var, 0.f);
    float rstd = rsqrtf(var + 1e-5f);

    half8_t afrag[4];
    const float* arow = hout + (size_t)row*128 + quad*8;
    #pragma unroll
    for (int kt = 0; kt < 4; ++kt) {
        int c = quad*8 + kt*32;
        const float4* v4 = (const float4*)(arow + kt*32);
        const float4* w4 = (const float4*)(lnw + c);
        const float4* b4 = (const float4*)(lnb + c);
        float4 v0 = v4[0], v1 = v4[1];
        float4 w0 = w4[0], w1 = w4[1];
        float4 bb0 = b4[0], bb1 = b4[1];
        float vv[8] = {v0.x,v0.y,v0.z,v0.w,v1.x,v1.y,v1.z,v1.w};
        float ww[8] = {w0.x,w0.y,w0.z,w0.w,w1.x,w1.y,w1.z,w1.w};
        float bz[8] = {bb0.x,bb0.y,bb0.z,bb0.w,bb1.x,bb1.y,bb1.z,bb1.w};
        #pragma unroll
        for (int j = 0; j < 8; ++j)
            afrag[kt][j] = (_Float16)((vv[j] - mean) * rstd * ww[j] + bz[j]);
    }
    #pragma unroll
    for (int nt = 0; nt < 16; ++nt) {
        floatx4 acc = {0.f, 0.f, 0.f, 0.f};
        const _Float16* brow = WT + (size_t)(nt*16 + r16)*128 + quad*8;
        #pragma unroll
        for (int kt = 0; kt < 4; ++kt) {
            half8_t bfrag = *(const half8_t*)(brow + kt*32);
            acc = __builtin_amdgcn_mfma_f32_16x16x32_f16(afrag[kt], bfrag, acc, 0, 0, 0);
        }
        int col = nt*16 + r16;
        float bv = b2[col];
        if (nt < 8) {
            #pragma unroll
            for (int r = 0; r < 4; ++r)
                xl_h[(size_t)(m0 + quad*4 + r)*128 + col] = (_Float16)(acc[r] + bv);
        } else {
            #pragma unroll
            for (int r = 0; r < 4; ++r)
                xr[(size_t)(m0 + quad*4 + r)*128 + (col-128)] = acc[r] + bv;
        }
    }
}

// ---------------- GATv2 aggregation: one wave per node.
// 16 lanes per edge (8 ch/lane, one 16B half8 gather), 4 edge slots/wave.
// Max-free softmax; packed-fp16 logit math (pk_add + and-mask + fdot2).
__global__ __launch_bounds__(256) void k_gat(
    const _Float16* __restrict__ xl_h, const float* __restrict__ xr,
    const int* __restrict__ row_ptr, const int* __restrict__ csr_src,
    const float* __restrict__ att, const float* __restrict__ bias,
    float* __restrict__ hout, float2* __restrict__ nstats) {
    int wave = (blockIdx.x * 256 + threadIdx.x) >> 6;
    int lane = threadIdx.x & 63;
    if (wave >= N_NODES) return;
    int i = wave;
    int slot = lane >> 4;        // edge slot 0..3
    int l16  = lane & 15;        // lane within edge group
    int c0   = l16 * 8;          // 8 contiguous channels per lane

    H8 atth, xrh;
    {
        const float4* a4 = (const float4*)(att + c0);
        const float4* r4 = (const float4*)(xr + (size_t)i*128 + c0);
        float4 a0 = a4[0], a1 = a4[1], r0 = r4[0], r1 = r4[1];
        float af[8] = {a0.x,a0.y,a0.z,a0.w,a1.x,a1.y,a1.z,a1.w};
        float rf[8] = {r0.x,r0.y,r0.z,r0.w,r1.x,r1.y,r1.z,r1.w};
        #pragma unroll
        for (int j = 0; j < 8; ++j) {
            atth.v[j] = (_Float16)af[j];
            xrh.v[j]  = (_Float16)rf[j];
        }
    }
    int p0 = row_ptr[i], p1 = row_ptr[i+1];

    float denom = 0.f;
    float acc[8];
    #pragma unroll
    for (int j = 0; j < 8; ++j) acc[j] = 0.f;

    for (int p = p0; p < p1; p += 8) {
        int e1 = p + slot, e2 = p + 4 + slot;
        int i1 = csr_src[(e1 < p1) ? e1 : (p1 - 1)];
        int i2 = csr_src[(e2 < p1) ? e2 : (p1 - 1)];
        H8 g1, g2, m1, m2;
        g1.v = *(const half8_t*)(xl_h + (size_t)i1*128 + c0);
        g2.v = *(const half8_t*)(xl_h + (size_t)i2*128 + c0);
        m1.v = g1.v + xrh.v;
        m2.v = g2.v + xrh.v;
        float pa1 = 0.f, pb1 = 0.f, pa2 = 0.f, pb2 = 0.f;
        #pragma unroll
        for (int j = 0; j < 4; ++j) {
            half2_t ab1 = __builtin_bit_cast(half2_t, m1.u[j] & 0x7FFF7FFFu);
            half2_t ab2 = __builtin_bit_cast(half2_t, m2.u[j] & 0x7FFF7FFFu);
            pa1 = __builtin_amdgcn_fdot2(m1.h2[j], atth.h2[j], pa1, false);
            pb1 = __builtin_amdgcn_fdot2(ab1,      atth.h2[j], pb1, false);
            pa2 = __builtin_amdgcn_fdot2(m2.h2[j], atth.h2[j], pa2, false);
            pb2 = __builtin_amdgcn_fdot2(ab2,      atth.h2[j], pb2, false);
        }
        float pt1 = 0.6f*pa1 + 0.4f*pb1;
        float pt2 = 0.6f*pa2 + 0.4f*pb2;
        pt1 += __shfl_xor(pt1, 1);  pt2 += __shfl_xor(pt2, 1);
        pt1 += __shfl_xor(pt1, 2);  pt2 += __shfl_xor(pt2, 2);
        float w1 = (e1 < p1) ? __expf(pt1) : 0.f;
        float w2 = (e2 < p1) ? __expf(pt2) : 0.f;
        denom += w1 + w2;
        #pragma unroll
        for (int j = 0; j < 8; ++j) {
            acc[j] = fmaf(w1, (float)g1.v[j], acc[j]);
            acc[j] = fmaf(w2, (float)g2.v[j], acc[j]);
        }
    }
    // merge the 4 edge-slot chains (lanes differing in bits 4,5)
    #pragma unroll
    for (int off = 16; off <= 32; off <<= 1) {
        denom += __shfl_xor(denom, off);
        #pragma unroll
        for (int j = 0; j < 8; ++j) acc[j] += __shfl_xor(acc[j], off);
    }
    float inv = 1.f / (denom + 1e-16f);
    float v[8];
    float s1 = 0.f, s2 = 0.f;
    #pragma unroll
    for (int j = 0; j < 8; ++j) {
        v[j] = acc[j] * inv + bias[c0 + j];
        s1 += v[j];
        s2 = fmaf(v[j], v[j], s2);
    }
    if (slot == 0) {
        float4* o4 = (float4*)(hout + (size_t)i*128 + c0);
        o4[0] = make_float4(v[0], v[1], v[2], v[3]);
        o4[1] = make_float4(v[4], v[5], v[6], v[7]);
    }
    #pragma unroll
    for (int off = 1; off < 16; off <<= 1) {
        s1 += __shfl_xor(s1, off);
        s2 += __shfl_xor(s2, off);
    }
    if (lane == 0) nstats[i] = make_float2(s1, s2);
}

// ---------------- per-graph reduction of node stats (plain stores) ----------
__global__ __launch_bounds__(256) void k_graph_red(
    const float2* __restrict__ nstats, const int* __restrict__ goff,
    float* __restrict__ gsum, float* __restrict__ gsumsq) {
    __shared__ float l1[256], l2[256];
    int g = blockIdx.x;
    int tid = threadIdx.x;
    int a = goff[g], b = goff[g+1];
    float s1 = 0.f, s2 = 0.f;
    for (int i = a + tid; i < b; i += 256) {
        float2 v = nstats[i];
        s1 += v.x; s2 += v.y;
    }
    l1[tid] = s1; l2[tid] = s2; __syncthreads();
    for (int off = 128; off > 0; off >>= 1) {
        if (tid < off) { l1[tid] += l1[tid+off]; l2[tid] += l2[tid+off]; }
        __syncthreads();
    }
    if (tid == 0) { gsum[g] = l1[0]; gsumsq[g] = l2[0]; }
}

// ---------------- final graph layernorm (fp16 out, feeds k_pairs only) -------
__global__ void k_ln(const float* __restrict__ hout, const int* __restrict__ batch,
                     const int* __restrict__ goff, const float* __restrict__ gsum,
                     const float* __restrict__ gsumsq, const float* __restrict__ w,
                     const float* __restrict__ b, _Float16* __restrict__ hb) {
    int idx = blockIdx.x*256 + threadIdx.x;
    if (idx >= N_NODES*128) return;
    int i = idx >> 7, c = idx & 127;
    int g = batch[i];
    float cnt = (float)(goff[g+1] - goff[g]) * 128.f;
    cnt = fmaxf(cnt, 1.f);
    float mean = gsum[g] / cnt;
    float var = gsumsq[g] / cnt - mean*mean;
    var = fmaxf(var, 0.f);
    float rstd = rsqrtf(var + 1e-5f);
    float v = (hout[idx] - mean) * rstd * w[c] + b[c];
    hb[idx] = (_Float16)v;
}

// ---------------- pair scoring: 16 lanes/pair, SINGLE gathered array,
// link_W folded into per-lane fp16 registers ----------
__global__ __launch_bounds__(256) void k_pairs(
    const _Float16* __restrict__ hb, const int* __restrict__ pi,
    const float* __restrict__ lW, const float* __restrict__ lb,
    float* __restrict__ out) {
    int grp = (blockIdx.x*256 + threadIdx.x) >> 4;
    int q = threadIdx.x & 15;
    if (grp >= N_PAIRS) return;
    H8 w;
    #pragma unroll
    for (int j = 0; j < 8; ++j) w.v[j] = (_Float16)lW[q*8 + j];
    int p0 = pi[grp], p1 = pi[N_PAIRS + grp];
    const half8_t* B = (const half8_t*)hb;
    H8 a, b, prod;
    a.v = B[(size_t)p0*16 + q];
    b.v = B[(size_t)p1*16 + q];
    prod.v = a.v * b.v;
    float part = 0.f;
    #pragma unroll
    for (int j = 0; j < 4; ++j)
        part = __builtin_amdgcn_fdot2(prod.h2[j], w.h2[j], part, false);
    part += __shfl_xor(part, 1);
    part += __shfl_xor(part, 2);
    part += __shfl_xor(part, 4);
    part += __shfl_xor(part, 8);
    if (q == 0) out[grp] = 1.f / (1.f + __expf(-(part + lb[0])));
}

extern "C" void kernel_launch(void* const* d_in, const int* in_sizes, int n_in,
                              void* d_out, int out_size, void* d_ws, size_t ws_size,
                              hipStream_t stream) {
    const float* x     = (const float*)d_in[0];
    const float* t     = (const float*)d_in[1];
    const int*   ei    = (const int*)  d_in[2];
    const int*   pi    = (const int*)  d_in[3];
    const int*   batch = (const int*)  d_in[4];
    const float* tW    = (const float*)d_in[5];
    const float* tb    = (const float*)d_in[6];
    const float* W0l   = (const float*)d_in[7];
    const float* b0l   = (const float*)d_in[8];
    const float* W0r   = (const float*)d_in[9];
    const float* b0r   = (const float*)d_in[10];
    const float* att0  = (const float*)d_in[11];
    const float* bias0 = (const float*)d_in[12];
    const float* Wl    = (const float*)d_in[13];
    const float* bl    = (const float*)d_in[14];
    const float* Wr    = (const float*)d_in[15];
    const float* br    = (const float*)d_in[16];
    const float* att   = (const float*)d_in[17];
    const float* bias  = (const float*)d_in[18];
    const float* lnw   = (const float*)d_in[19];
    const float* lnb   = (const float*)d_in[20];
    const float* lW    = (const float*)d_in[21];
    const float* lb    = (const float*)d_in[22];
    float* out = (float*)d_out;

    char* ws = (char*)d_ws;
    size_t off = 0;
    auto walloc = [&](size_t bytes) -> void* {
        void* p = ws + off;
        off += (bytes + 255) & ~(size_t)255;
        return p;
    };
    _Float16*  h0h     = (_Float16*) walloc((size_t)N_NODES*384*2);
    float*     hout    = (float*)    walloc((size_t)N_NODES*128*4);
    _Float16*  xl_h    = (_Float16*) walloc((size_t)N_NODES*128*2);
    float*     xr      = (float*)    walloc((size_t)N_NODES*128*4);
    _Float16*  hb      = (_Float16*) walloc((size_t)N_NODES*128*2);
    int*       degp    = (int*)      walloc((size_t)N_NODES*CPAD*4); // padded; reused as cursor
    int*       row_ptr = (int*)      walloc((size_t)(N_NODES+1)*4);
    int*       csr_src = (int*)      walloc((size_t)E_TOT*4);
    int*       bsums   = (int*)      walloc(256*4);
    int*       goff    = (int*)      walloc(64*4);
    float2*    nstats  = (float2*)   walloc((size_t)N_NODES*8);
    float*     stats   = (float*)    walloc(2*64*4);              // [sum|sumsq][64]
    _Float16*  WT0     = (_Float16*) walloc(256*384*2);
    _Float16*  WT123   = (_Float16*) walloc(3*256*128*2);
    float*     b2      = (float*)    walloc(4*256*4);

    hipMemsetAsync(degp, 0, (size_t)N_NODES*CPAD*4, stream);

    k_time_embed<<<N_NODES, 256, 0, stream>>>(x, t, tW, tb, h0h);
    k_cvt_w<<<(256*384+255)/256, 256, 0, stream>>>(W0l, W0r, b0l, b0r, 384, WT0, b2);
    for (int l = 0; l < 3; ++l)
        k_cvt_w<<<(256*128+255)/256, 256, 0, stream>>>(
            Wl + (size_t)l*128*128, Wr + (size_t)l*128*128,
            bl + l*128, br + l*128, 128, WT123 + (size_t)l*256*128, b2 + (l+1)*256);
    k_edge_hist<<<(E_TOT+255)/256, 256, 0, stream>>>(ei, degp);
    k_goff<<<SCAN_NB, 256, 0, stream>>>(batch, goff);
    k_scan1<<<SCAN_NB, 256, 0, stream>>>(degp, row_ptr, bsums);
    k_scan2<<<1, 256, 0, stream>>>(bsums, SCAN_NB);
    k_scan3<<<SCAN_NB, 256, 0, stream>>>(row_ptr, bsums, degp);  // degp becomes cursor
    k_scatter<<<(E_TOT+1023)/1024, 256, 0, stream>>>(ei, degp, csr_src);

    float* gsum   = stats;
    float* gsumsq = stats + 64;
    const int GEMM_BLOCKS = (N_NODES/16 + 3) / 4;   // 4 waves/block, 16 rows/wave
    for (int L = 0; L < 4; ++L) {
        if (L == 0)
            k_gemm_mfma<384><<<GEMM_BLOCKS, 256, 0, stream>>>(h0h, WT0, b2, xl_h, xr);
        else
            k_gemm_ln_mfma<<<GEMM_BLOCKS, 256, 0, stream>>>(
                hout, batch, goff, gsum, gsumsq, lnw + (L-1)*128, lnb + (L-1)*128,
                WT123 + (size_t)(L-1)*256*128, b2 + L*256, xl_h, xr);
        const float* attL  = (L == 0) ? att0  : att  + (size_t)(L-1)*128;
        const float* biasL = (L == 0) ? bias0 : bias + (size_t)(L-1)*128;
        k_gat<<<N_NODES/4, 256, 0, stream>>>(xl_h, xr, row_ptr, csr_src, attL, biasL,
                                             hout, nstats);
        k_graph_red<<<N_GRAPHS, 256, 0, stream>>>(nstats, goff, gsum, gsumsq);
    }
    k_ln<<<(N_NODES*128+255)/256, 256, 0, stream>>>(hout, batch, goff, gsum, gsumsq,
                                                    lnw + 3*128, lnb + 3*128, hb);
    k_pairs<<<((size_t)N_PAIRS*16 + 255)/256, 256, 0, stream>>>(hb, pi, lW, lb, out);
}